// Round 16
// baseline (525.317 us; speedup 1.0000x reference)
//
#include <hip/hip_runtime.h>
#include <hip/hip_bf16.h>

using bf16 = __hip_bfloat16;
using s16x4 = __attribute__((ext_vector_type(4))) short;
using s16x8 = __attribute__((ext_vector_type(8))) short;
using f32x4 = __attribute__((ext_vector_type(4))) float;

#define DI __device__ __forceinline__

template <int N> DI void wvm() {
    if constexpr (N == 8) asm volatile("s_waitcnt vmcnt(8)" ::: "memory");
    else if constexpr (N == 4) asm volatile("s_waitcnt vmcnt(4)" ::: "memory");
    else if constexpr (N == 2) asm volatile("s_waitcnt vmcnt(2)" ::: "memory");
    else asm volatile("s_waitcnt vmcnt(0)" ::: "memory");
}

DI float b2f(short s) { union { unsigned u; float f; } z; z.u = ((unsigned)(unsigned short)s) << 16; return z.f; }
DI short f2b(float f) { bf16 t = __float2bfloat16(f); return *(short*)&t; }

// fast gelu: tanh form, |err| ~1e-3 absolute, far under threshold
DI float gelu_f(float x) {
    const float t = 0.7978845608f * x * (1.f + 0.044715f * x * x);
    const float e = __expf(2.f * t);
    const float th = 1.f - 2.f / (e + 1.f);
    return 0.5f * x * (1.f + th);
}

DI void ld8(const bf16* p, float* f) {
    s16x8 x = *(const s16x8*)(const void*)p;
#pragma unroll
    for (int c = 0; c < 8; c++) f[c] = b2f(x[c]);
}
DI void ld8(const float* p, float* f) {
    float4 a = *(const float4*)p, b = *(const float4*)(p + 4);
    f[0]=a.x; f[1]=a.y; f[2]=a.z; f[3]=a.w; f[4]=b.x; f[5]=b.y; f[6]=b.z; f[7]=b.w;
}

typedef const __attribute__((address_space(1))) void* gp_t;
typedef __attribute__((address_space(3))) void* lp_t;
DI void gload_lds16(const void* g, void* l) {
    __builtin_amdgcn_global_load_lds((gp_t)g, (lp_t)l, 16, 0, 0);
}

// ---------------- diagnostic ----------------
__global__ void diag_k(float* out, float v) { out[0] = v; }

// ---------------- fp32 -> bf16 weight conversion (8/thread) ----------------
__global__ void f2bf_k(const float* __restrict__ in, bf16* __restrict__ out, int n) {
    int i = (blockIdx.x * 256 + threadIdx.x) * 8;
    if (i >= n) return;
    float f[8];
    ld8(in + i, f);
    s16x8 o;
#pragma unroll
    for (int c = 0; c < 8; c++) o[c] = f2b(f[c]);
    *(s16x8*)(void*)(out + i) = o;
}

// ---------------- depthwise 3x3 conv v4 ----------------
DI void tap10(const float* r, float w0, float w1, float w2, float* acc) {
#pragma unroll
    for (int i = 0; i < 8; i++)
        acc[i] += w0 * r[i] + w1 * r[i + 1] + w2 * r[i + 2];
}

template <typename TI, typename TO, bool RESID, int CPL>
__global__ __launch_bounds__(256) void conv4_k(
    const TI* in, long rs, long coff,
    const float* __restrict__ w, const float* __restrict__ bias,
    TO* out, long ors, int gshift)
{
    constexpr int CH = 64 * CPL;
    constexpr int ECNT = CH / 8;
    __shared__ float buf[2][CH][33];
    const int t = threadIdx.x;
    const int band = blockIdx.x & 3;
    const int cg = (blockIdx.x >> 2) & ((1 << gshift) - 1);
    const int img = blockIdx.x >> (2 + gshift);
    const int y0 = band * 8;

    const int spx = t >> 3;
    const int sce = (t & 7) * ECNT;
    const TI* gsrc = in + ((long)img << 10) * rs + coff + (long)cg * CH + sce;

    const int c = t & 63;
    const int xb = (t >> 6) * 8;

    float wv9[9][CPL], bw[CPL];
#pragma unroll
    for (int p = 0; p < CPL; p++) {
        const int gch = cg * CH + c * CPL + p;
#pragma unroll
        for (int j = 0; j < 9; j++) wv9[j][p] = w[gch * 9 + j];
        bw[p] = bias[gch];
    }

    auto stage = [&](int row) {
        float f[ECNT];
        ld8(gsrc + (long)(row * 32 + spx) * rs, f);
        if constexpr (ECNT == 16) ld8(gsrc + (long)(row * 32 + spx) * rs + 8, f + 8);
        float* d = &buf[row & 1][0][0];
#pragma unroll
        for (int k = 0; k < ECNT; k++) {
            const int ch = sce + k;
            const int rr = (CPL == 2) ? ((ch & 1) * 64 + (ch >> 1)) : ch;
            d[rr * 33 + spx] = f[k];
        }
    };
    auto slice = [&](int row, float r[CPL][10]) {
#pragma unroll
        for (int p = 0; p < CPL; p++) {
            const float* s = &buf[row & 1][c + p * 64][0];
            r[p][0] = (xb == 0) ? 0.f : s[xb - 1];
#pragma unroll
            for (int i = 0; i < 8; i++) r[p][1 + i] = s[xb + i];
            r[p][9] = (xb + 8 >= 32) ? 0.f : s[xb + 8];
        }
    };
    auto zero = [&](float r[CPL][10]) {
#pragma unroll
        for (int p = 0; p < CPL; p++)
#pragma unroll
            for (int i = 0; i < 10; i++) r[p][i] = 0.f;
    };

    float r0[CPL][10], r1[CPL][10], r2[CPL][10];
    if (y0 > 0) stage(y0 - 1);
    __syncthreads();
    if (y0 > 0) slice(y0 - 1, r0); else zero(r0);
    stage(y0);
    __syncthreads();
    slice(y0, r1);

    for (int y = y0; y < y0 + 8; ++y) {
        const int yn = y + 1;
        if (yn <= 31) stage(yn);
        __syncthreads();
        if (yn <= 31) slice(yn, r2); else zero(r2);
        float acc[CPL][8];
#pragma unroll
        for (int p = 0; p < CPL; p++) {
#pragma unroll
            for (int i = 0; i < 8; i++) acc[p][i] = bw[p];
            tap10(r0[p], wv9[0][p], wv9[1][p], wv9[2][p], acc[p]);
            tap10(r1[p], wv9[3][p], wv9[4][p], wv9[5][p], acc[p]);
            tap10(r2[p], wv9[6][p], wv9[7][p], wv9[8][p], acc[p]);
            if (RESID) {
#pragma unroll
                for (int i = 0; i < 8; i++) acc[p][i] += r1[p][i + 1];
            }
        }
        TO* o = out + ((long)(img * 1024 + y * 32 + xb)) * ors + (long)cg * CH + c * CPL;
#pragma unroll
        for (int i = 0; i < 8; i++) {
            if constexpr (CPL == 2 && sizeof(TO) == 2) {
                const unsigned u = (unsigned)(unsigned short)f2b(acc[0][i]) |
                                   ((unsigned)(unsigned short)f2b(acc[1][i]) << 16);
                *(unsigned*)(void*)(o + (long)i * ors) = u;
            } else {
                o[(long)i * ors] = (TO)acc[0][i];
            }
        }
#pragma unroll
        for (int p = 0; p < CPL; p++)
#pragma unroll
            for (int i = 0; i < 10; i++) { r0[p][i] = r1[p][i]; r1[p][i] = r2[p][i]; }
    }
}

// ---------------- LayerNorm over C=512, fp32 in -> bf16 out ----------------
__global__ __launch_bounds__(256) void ln_k(const float* __restrict__ x,
                                            const float* __restrict__ w,
                                            const float* __restrict__ bp,
                                            bf16* __restrict__ out)
{
    const size_t row = blockIdx.x * 4 + (threadIdx.x >> 6);
    const int t = threadIdx.x & 63;
    const float* xr = x + row * 512;
    alignas(16) float v[8];
    *(float4*)&v[0] = *(const float4*)(xr + t * 8);
    *(float4*)&v[4] = *(const float4*)(xr + t * 8 + 4);
    float s = 0.f;
#pragma unroll
    for (int j = 0; j < 8; j++) s += v[j];
#pragma unroll
    for (int mm = 32; mm; mm >>= 1) s += __shfl_xor(s, mm);
    const float mu = s * (1.f / 512.f);
    float q = 0.f;
#pragma unroll
    for (int j = 0; j < 8; j++) { v[j] -= mu; q += v[j] * v[j]; }
#pragma unroll
    for (int mm = 32; mm; mm >>= 1) q += __shfl_xor(q, mm);
    const float rstd = rsqrtf(q * (1.f / 512.f) + 1e-6f);
    alignas(16) float wv[8], bv[8];
    *(float4*)&wv[0] = *(const float4*)(w + t * 8);
    *(float4*)&wv[4] = *(const float4*)(w + t * 8 + 4);
    *(float4*)&bv[0] = *(const float4*)(bp + t * 8);
    *(float4*)&bv[4] = *(const float4*)(bp + t * 8 + 4);
    alignas(16) bf16 o[8];
#pragma unroll
    for (int j = 0; j < 8; j++) o[j] = __float2bfloat16(v[j] * rstd * wv[j] + bv[j]);
    *(uint4*)(out + row * 512 + t * 8) = *(const uint4*)o;
}

// ---------------- 8-phase 256x256 bf16 MFMA GEMM -----------------------------
// BK=64, 8 waves 2Mx4N, 128KB LDS, XCD-swizzled 1D grid.
// EPI 0: bf16. 1: +bias gelu bf16. 2: +bias +resid fp32.
template <int EPI, int K, int NY>
__global__ __launch_bounds__(512) void gemm8p_k(
    const bf16* __restrict__ A, const bf16* __restrict__ Bw,
    const float* __restrict__ bias, const float* resid,
    bf16* __restrict__ outb, float* outf, int M, int Nn)
{
    constexpr int KT = K / 64;
    __shared__ __align__(16) char lds[131072];
    char* ldsA = lds;
    char* ldsB = lds + 65536;
    const int t = threadIdx.x;
    const int lane = t & 63;
    const int w = t >> 6;
    const int wr = w >> 2, wc = w & 3;
    const int nwg = 128 * NY;
    const int swz = (blockIdx.x & 7) * (nwg >> 3) + (blockIdx.x >> 3);
    const int m0 = (swz / NY) * 256;
    const int n0 = (swz % NY) * 256;
    const int lr = lane & 15, lg = lane >> 4;

    f32x4 acc[8][4] = {};

    const int srow = lane >> 3;
    const int ssrc = 8 * ((lane & 7) ^ srow);

    auto SA = [&](int b, int kt, int h) {
#pragma unroll
        for (int j = 0; j < 2; j++) {
            const int lrow0 = j * 64 + w * 8;
            const int R0 = j * 128 + h * 64 + (lrow0 & 63);
            gload_lds16(A + (size_t)(m0 + R0 + srow) * K + kt * 64 + ssrc,
                        ldsA + ((b * 2 + h) * 128 + lrow0) * 128);
        }
    };
    auto SB = [&](int b, int kt, int h) {
#pragma unroll
        for (int j = 0; j < 2; j++) {
            const int lrow0 = j * 64 + w * 8;
            const int R0 = (lrow0 >> 5) * 64 + h * 32 + (lrow0 & 31);
            gload_lds16(Bw + (size_t)(n0 + R0 + srow) * K + kt * 64 + ssrc,
                        ldsB + ((b * 2 + h) * 128 + lrow0) * 128);
        }
    };
    auto RA = [&](int b, int h, int m, int ks) -> s16x8 {
        return *(const s16x8*)(ldsA + ((b * 2 + h) * 128 + wr * 64 + m * 16 + lr) * 128
                               + (((ks * 4 + lg) ^ (lr & 7)) << 4));
    };
    auto RB = [&](int b, int h, int n, int ks) -> s16x8 {
        return *(const s16x8*)(ldsB + ((b * 2 + h) * 128 + wc * 32 + n * 16 + lr) * 128
                               + (((ks * 4 + lg) ^ (lr & 7)) << 4));
    };
    auto MM = [&](int mb, int nb, s16x8 (&a)[2][4], s16x8 (&b)[2][2]) {
#pragma unroll
        for (int ks = 0; ks < 2; ks++)
#pragma unroll
            for (int m = 0; m < 4; m++)
#pragma unroll
                for (int n = 0; n < 2; n++)
                    acc[mb + m][nb + n] =
                        __builtin_amdgcn_mfma_f32_16x16x32_bf16(a[ks][m], b[ks][n], acc[mb + m][nb + n], 0, 0, 0);
    };

    SA(0, 0, 0); SB(0, 0, 0); SA(0, 0, 1); SB(0, 0, 1);
    SA(1, 1, 0); SB(1, 1, 0);
    wvm<8>();
    __builtin_amdgcn_s_barrier();

    s16x8 aLo[2][4], aHi[2][4], bLo[2][2], bHi[2][2];
    auto TILE = [&](int kt) {
        const int b = kt & 1;
#pragma unroll
        for (int ks = 0; ks < 2; ks++) {
#pragma unroll
            for (int m = 0; m < 4; m++) aLo[ks][m] = RA(b, 0, m, ks);
#pragma unroll
            for (int n = 0; n < 2; n++) bLo[ks][n] = RB(b, 0, n, ks);
        }
        if (kt + 1 < KT) SA(b ^ 1, kt + 1, 1);
        __builtin_amdgcn_s_barrier();
        __builtin_amdgcn_s_setprio(1);
        MM(0, 0, aLo, bLo);
        __builtin_amdgcn_s_setprio(0);
        if (kt + 1 < KT) wvm<8>(); else wvm<2>();
        __builtin_amdgcn_s_barrier();
#pragma unroll
        for (int ks = 0; ks < 2; ks++)
#pragma unroll
            for (int m = 0; m < 4; m++) aHi[ks][m] = RA(b, 1, m, ks);
        if (kt + 1 < KT) SB(b ^ 1, kt + 1, 1);
        __builtin_amdgcn_s_barrier();
        __builtin_amdgcn_s_setprio(1);
        MM(4, 0, aHi, bLo);
        __builtin_amdgcn_s_setprio(0);
        if (kt + 1 < KT) wvm<8>(); else wvm<0>();
        __builtin_amdgcn_s_barrier();
#pragma unroll
        for (int ks = 0; ks < 2; ks++)
#pragma unroll
            for (int n = 0; n < 2; n++) bHi[ks][n] = RB(b, 1, n, ks);
        if (kt + 2 < KT) SA(b, kt + 2, 0);
        __builtin_amdgcn_s_barrier();
        __builtin_amdgcn_s_setprio(1);
        MM(4, 2, aHi, bHi);
        __builtin_amdgcn_s_setprio(0);
        __builtin_amdgcn_s_barrier();
        if (kt + 2 < KT) SB(b, kt + 2, 0);
        __builtin_amdgcn_s_barrier();
        __builtin_amdgcn_s_setprio(1);
        MM(0, 2, aLo, bHi);
        __builtin_amdgcn_s_setprio(0);
        if (kt + 2 < KT) { wvm<8>(); __builtin_amdgcn_s_barrier(); }
        else if (kt + 1 < KT) { wvm<4>(); __builtin_amdgcn_s_barrier(); }
    };

#pragma unroll
    for (int kt = 0; kt < KT; ++kt) TILE(kt);

#pragma unroll
    for (int i = 0; i < 8; i++) {
#pragma unroll
        for (int j = 0; j < 4; j++) {
            const int col = n0 + wc * 64 + j * 16 + lr;
            float bcol = 0.f;
            if constexpr (EPI >= 1) bcol = bias[col];
#pragma unroll
            for (int r = 0; r < 4; r++) {
                const int row = m0 + wr * 128 + i * 16 + lg * 4 + r;
                float v = acc[i][j][r] + bcol;
                const size_t idx = (size_t)row * Nn + col;
                if (EPI == 2) outf[idx] = v + resid[idx];
                else outb[idx] = __float2bfloat16(EPI == 1 ? gelu_f(v) : v);
            }
        }
    }
}

// ---------------- fc2 kernel: BM=128 BN=256 BK=32, 48KB LDS, 2 blocks/CU ----
// 4 waves, each 128x64 out. Dual-A (h2a: kt<32, h2b: kt>=32, lda=1024).
// r9-style loop: STAGE(next) -> COMPUTE(cur) -> vmcnt(0) -> barrier.
// Swizzle: src k = 8*((lane&3)^((lane>>3)&3)); read slot = lg ^ ((lr>>1)&3).
__global__ __launch_bounds__(256) void gemmfc3_k(
    const bf16* __restrict__ A, const bf16* __restrict__ A2,
    const bf16* __restrict__ Bw, const float* __restrict__ bias,
    const float* resid, float* outf, int M, int Nn)
{
    constexpr int KT = 64;        // K=2048, BK=32
    __shared__ __align__(16) short As[2][128 * 32];
    __shared__ __align__(16) short Bs[2][256 * 32];
    const int t = threadIdx.x;
    const int lane = t & 63;
    const int wv = t >> 6;        // wave 0..3 = N-column group
    const int nwg = 512;          // 256 m-blocks x 2 n-blocks
    const int swz = (blockIdx.x & 7) * (nwg >> 3) + (blockIdx.x >> 3);
    const int m0 = (swz >> 1) * 128;
    const int n0 = (swz & 1) * 256;
    const int lr = lane & 15, lg = lane >> 4;

    f32x4 acc[8][4] = {};

    const int srow = lane >> 2;                    // 0..15
    const int sk = 8 * ((lane & 3) ^ ((lane >> 3) & 3));
    const int rsw = (lr >> 1) & 3;

    auto STAGE = [&](int buf, int kt) {
        const bf16* Ab = (kt < 32) ? A : A2;
        const int kc = ((kt < 32) ? kt : kt - 32) * 32 + sk;
        // A: 8 loads (2/wave), rows wv*32 + {0,16} + srow
#pragma unroll
        for (int j = 0; j < 2; j++) {
            const int r = wv * 32 + j * 16 + srow;
            gload_lds16(Ab + (size_t)(m0 + r) * 1024 + kc,
                        (char*)&As[buf][0] + (wv * 32 + j * 16) * 64);
        }
        // B: 16 loads (4/wave), rows wv*64 + {0,16,32,48} + srow
#pragma unroll
        for (int j = 0; j < 4; j++) {
            const int r = wv * 64 + j * 16 + srow;
            gload_lds16(Bw + (size_t)(n0 + r) * 2048 + kt * 32 + sk,
                        (char*)&Bs[buf][0] + (wv * 64 + j * 16) * 64);
        }
    };

    auto COMPUTE = [&](int buf) {
        s16x8 aF[8], bF[4];
#pragma unroll
        for (int i = 0; i < 8; i++)
            aF[i] = *(const s16x8*)((const char*)&As[buf][0] + (i * 16 + lr) * 64 + ((lg ^ rsw) << 4));
#pragma unroll
        for (int j = 0; j < 4; j++)
            bF[j] = *(const s16x8*)((const char*)&Bs[buf][0] + (wv * 64 + j * 16 + lr) * 64 + ((lg ^ rsw) << 4));
#pragma unroll
        for (int i = 0; i < 8; i++)
#pragma unroll
            for (int j = 0; j < 4; j++)
                acc[i][j] = __builtin_amdgcn_mfma_f32_16x16x32_bf16(aF[i], bF[j], acc[i][j], 0, 0, 0);
    };

    STAGE(0, 0);
    wvm<0>();
    __builtin_amdgcn_s_barrier();
    for (int kt = 0; kt < KT; ++kt) {
        if (kt + 1 < KT) STAGE((kt + 1) & 1, kt + 1);
        COMPUTE(kt & 1);
        wvm<0>();
        __builtin_amdgcn_s_barrier();
    }

#pragma unroll
    for (int i = 0; i < 8; i++) {
#pragma unroll
        for (int j = 0; j < 4; j++) {
            const int col = n0 + wv * 64 + j * 16 + lr;
            const float bcol = bias[col];
#pragma unroll
            for (int r = 0; r < 4; r++) {
                const int row = m0 + i * 16 + lg * 4 + r;
                const size_t idx = (size_t)row * Nn + col;
                outf[idx] = acc[i][j][r] + bcol + resid[idx];
            }
        }
    }
}

// ---------------- ktv v2: MFMA over tokens, fused softmax-denominator -------
__global__ __launch_bounds__(256) void ktv2_k(const bf16* __restrict__ qkv,
                                              bf16* __restrict__ ktvT)
{
    __shared__ __align__(16) char P[64 * 128];
    __shared__ __align__(16) char Vt[64 * 128];
    __shared__ float csl[64 * 5];
    const int t = threadIdx.x;
    const int b = blockIdx.x >> 3, hh = blockIdx.x & 7;
    const int lane = t & 63, w = t >> 6;
    const int lr = lane & 15, lg = lane >> 4;

    const int n_r = t >> 2;
    const int k0 = (t & 3) * 16;
    const bf16* kbase = qkv + (size_t)(b * 1024) * 1536 + 512 + hh * 64 + k0;
    const bf16* vbase = kbase + 512;

    const int kq = t & 63, qq = t >> 6;
    float cacc = 0.f;

    f32x4 acc[4] = {};

    for (int n0 = 0; n0 < 1024; n0 += 64) {
        const uint4 ka = *(const uint4*)(kbase + (size_t)(n0 + n_r) * 1536);
        const uint4 kb2 = *(const uint4*)(kbase + (size_t)(n0 + n_r) * 1536 + 8);
        const uint4 va = *(const uint4*)(vbase + (size_t)(n0 + n_r) * 1536);
        const uint4 vb2 = *(const uint4*)(vbase + (size_t)(n0 + n_r) * 1536 + 8);
        __syncthreads();
        {
            const short* ke = (const short*)&ka;
            const short* ke2 = (const short*)&kb2;
            const short* ve = (const short*)&va;
            const short* ve2 = (const short*)&vb2;
            const int nslot = ((n_r >> 3) << 4);
            const int nbyte = (n_r & 7) * 2;
#pragma unroll
            for (int j = 0; j < 16; j++) {
                const int row = k0 + j;
                const short kv = j < 8 ? ke[j] : ke2[j - 8];
                const short vv = j < 8 ? ve[j] : ve2[j - 8];
                const int off = row * 128 + (nslot ^ ((row & 7) << 4)) + nbyte;
                *(short*)(P + off) = f2b(__expf(b2f(kv)));
                *(short*)(Vt + off) = vv;
            }
        }
        __syncthreads();
        {
            const char* pr = P + kq * 128;
            const int sw = (kq & 7) << 4;
            s16x8 x0 = *(const s16x8*)(pr + (((qq * 2) << 4) ^ sw));
            s16x8 x1 = *(const s16x8*)(pr + (((qq * 2 + 1) << 4) ^ sw));
#pragma unroll
            for (int j = 0; j < 8; j++) cacc += b2f(x0[j]) + b2f(x1[j]);
        }
#pragma unroll
        for (int ks2 = 0; ks2 < 2; ks2++) {
            s16x8 aF = *(const s16x8*)(Vt + (w * 16 + lr) * 128 + (((ks2 * 4 + lg) ^ (lr & 7)) << 4));
            s16x8 bF[4];
#pragma unroll
            for (int j = 0; j < 4; j++)
                bF[j] = *(const s16x8*)(P + (j * 16 + lr) * 128 + (((ks2 * 4 + lg) ^ (lr & 7)) << 4));
#pragma unroll
            for (int j = 0; j < 4; j++)
                acc[j] = __builtin_amdgcn_mfma_f32_16x16x32_bf16(aF, bF[j], acc[j], 0, 0, 0);
        }
    }
    __syncthreads();
    csl[kq * 5 + qq] = cacc;
    __syncthreads();
    if (t < 64) csl[t * 5 + 4] = csl[t * 5] + csl[t * 5 + 1] + csl[t * 5 + 2] + csl[t * 5 + 3];
    __syncthreads();

    bf16* o = ktvT + (size_t)(b * 8 + hh) * 4096;
#pragma unroll
    for (int j = 0; j < 4; j++) {
        const int col = j * 16 + lr;
        const float sc = 0.125f / csl[col * 5 + 4];
#pragma unroll
        for (int r = 0; r < 4; r++) {
            const int vrow = w * 16 + lg * 4 + r;
            o[vrow * 64 + col] = __float2bfloat16(acc[j][r] * sc);
        }
    }
}

// ---------------- attnout v2: MFMA q@ktvT + fused crpe + residual -----------
__global__ __launch_bounds__(256) void attnout2_k(
    float* xs, const bf16* __restrict__ qkv,
    const bf16* __restrict__ ktvT, const bf16* __restrict__ vc)
{
    __shared__ __align__(16) char qs[256 * 128];
    __shared__ __align__(16) char ks[64 * 128];
    const int t = threadIdx.x;
    const int bid = blockIdx.x;
    const int b = bid >> 5, hh = (bid >> 2) & 7, nc = bid & 3;
    const int n0 = nc * 256;
    const int lane = t & 63, w = t >> 6;
    const int lr = lane & 15, lg = lane >> 4;

    {
        const int r0 = t >> 3, sl = t & 7;
#pragma unroll
        for (int it = 0; it < 8; it++) {
            const int row = it * 32 + r0;
            const uint4 v = *(const uint4*)(qkv + ((size_t)(b * 1024 + n0 + row)) * 1536 + hh * 64 + sl * 8);
            *(uint4*)(qs + row * 128 + ((sl ^ (row & 7)) << 4)) = v;
        }
#pragma unroll
        for (int it = 0; it < 2; it++) {
            const int u = it * 256 + t;
            const int vr = u >> 3, sl2 = u & 7;
            const uint4 vv = *(const uint4*)(ktvT + (size_t)(b * 8 + hh) * 4096 + vr * 64 + sl2 * 8);
            *(uint4*)(ks + vr * 128 + ((sl2 ^ (vr & 7)) << 4)) = vv;
        }
    }
    __syncthreads();

    f32x4 acc[4][4] = {};
    s16x8 aF[2][4], bF[2][4];
#pragma unroll
    for (int ksi = 0; ksi < 2; ksi++) {
#pragma unroll
        for (int m = 0; m < 4; m++) {
            const int row = w * 64 + m * 16 + lr;
            aF[ksi][m] = *(const s16x8*)(qs + row * 128 + (((ksi * 4 + lg) ^ (lr & 7)) << 4));
        }
#pragma unroll
        for (int j = 0; j < 4; j++) {
            const int vr = j * 16 + lr;
            bF[ksi][j] = *(const s16x8*)(ks + vr * 128 + (((ksi * 4 + lg) ^ (lr & 7)) << 4));
        }
    }
#pragma unroll
    for (int ksi = 0; ksi < 2; ksi++)
#pragma unroll
        for (int m = 0; m < 4; m++)
#pragma unroll
            for (int j = 0; j < 4; j++)
                acc[m][j] = __builtin_amdgcn_mfma_f32_16x16x32_bf16(aF[ksi][m], bF[ksi][j], acc[m][j], 0, 0, 0);

#pragma unroll
    for (int m = 0; m < 4; m++) {
#pragma unroll
        for (int j = 0; j < 4; j++) {
#pragma unroll
            for (int r = 0; r < 4; r++) {
                const int lrow = w * 64 + m * 16 + lg * 4 + r;
                const int col = j * 16 + lr;
                const size_t idx = ((size_t)(b * 1024 + n0 + lrow)) * 512 + hh * 64 + col;
                const short qv = *(const short*)(qs + lrow * 128 + ((((col >> 3) ^ (lrow & 7)) << 4)) + (col & 7) * 2);
                xs[idx] = xs[idx] + acc[m][j][r] + b2f(qv) * __bfloat162float(vc[idx]);
            }
        }
    }
}

// ---------------- workspace layout (bytes), full-batch ----------------------
static constexpr size_t OFF_WQ   = 0;
static constexpr size_t OFF_W1   = 1572864;
static constexpr size_t OFF_W2   = 3670016;
static constexpr size_t OFF_CUR  = 5767168;
static constexpr size_t OFF_H2B  = 5767168;
static constexpr size_t OFF_QKV  = 72876032;
static constexpr size_t OFF_HG   = 72876032;
static constexpr size_t OFF_VC   = 173539328;
static constexpr size_t OFF_H2A  = 139984896;
static constexpr size_t OFF_KTV  = 207093760;
static constexpr size_t WS_NEED  = 207618048;   // ~198MB (ws >= 215.5MB confirmed)

extern "C" void kernel_launch(void* const* d_in, const int* in_sizes, int n_in,
                              void* d_out, int out_size, void* d_ws, size_t ws_size,
                              hipStream_t stream)
{
    const float* x     = (const float*)d_in[0];
    const float* cpe_w = (const float*)d_in[1];
    const float* cpe_b = (const float*)d_in[2];
    const float* ln1_w = (const float*)d_in[3];
    const float* ln1_b = (const float*)d_in[4];
    const float* qkv_w = (const float*)d_in[5];
    const float* crpe_w= (const float*)d_in[6];
    const float* crpe_b= (const float*)d_in[7];
    const float* ln2_w = (const float*)d_in[8];
    const float* ln2_b = (const float*)d_in[9];
    const float* fc1_w = (const float*)d_in[10];
    const float* fc1_b = (const float*)d_in[11];
    const float* dw_w  = (const float*)d_in[12];
    const float* dw_b  = (const float*)d_in[13];
    const float* fc2_w = (const float*)d_in[14];
    const float* fc2_b = (const float*)d_in[15];
    float* spine = (float*)d_out;
    char* ws = (char*)d_ws;

    if (ws_size < WS_NEED) {
        diag_k<<<1, 1, 0, stream>>>(spine, (float)ws_size);
        return;
    }

    bf16*  wq   = (bf16*)(ws + OFF_WQ);
    bf16*  w1   = (bf16*)(ws + OFF_W1);
    bf16*  w2b  = (bf16*)(ws + OFF_W2);
    bf16*  cur  = (bf16*)(ws + OFF_CUR);
    bf16*  qkv  = (bf16*)(ws + OFF_QKV);
    bf16*  vc   = (bf16*)(ws + OFF_VC);
    bf16*  ktvT = (bf16*)(ws + OFF_KTV);
    bf16*  hg   = (bf16*)(ws + OFF_HG);
    bf16*  h2a  = (bf16*)(ws + OFF_H2A);
    bf16*  h2b  = (bf16*)(ws + OFF_H2B);

    // weights -> bf16 (w2 native [512][2048])
    f2bf_k<<<(1536 * 512 / 8 + 255) / 256, 256, 0, stream>>>(qkv_w, wq, 1536 * 512);
    f2bf_k<<<(2048 * 512 / 8 + 255) / 256, 256, 0, stream>>>(fc1_w, w1, 2048 * 512);
    f2bf_k<<<(2048 * 512 / 8 + 255) / 256, 256, 0, stream>>>(fc2_w, w2b, 512 * 2048);

    // CPE (fp32, 64-ch groups): spine = x + dwconv(x) + cpe_b
    conv4_k<float, float, true, 1><<<32 * 8 * 4, 256, 0, stream>>>(x, 512, 0, cpe_w, cpe_b, spine, 512, 3);

    const int M = 32768;
    // LN1
    ln_k<<<M / 4, 256, 0, stream>>>(spine, ln1_w, ln1_b, cur);
    // qkv: 768 blocks (XCD-swizzled)
    gemm8p_k<0, 512, 6><<<768, 512, 0, stream>>>(cur, wq, nullptr, nullptr, qkv, nullptr, M, 1536);
    // ktv (MFMA, fused denom): 256 blocks
    ktv2_k<<<256, 256, 0, stream>>>(qkv, ktvT);
    // crpe conv on v
    conv4_k<bf16, bf16, false, 2><<<32 * 4 * 4, 256, 0, stream>>>(qkv, 1536, 1024, crpe_w, crpe_b, vc, 512, 2);
    // attention output (MFMA), in place on spine
    attnout2_k<<<32 * 8 * 4, 256, 0, stream>>>(spine, qkv, ktvT, vc);
    // LN2
    ln_k<<<M / 4, 256, 0, stream>>>(spine, ln2_w, ln2_b, cur);

    // MLP: fc1(h0)->conv(h0)->fc1(h1)->conv(h1)->fc2(dual, 2 blocks/CU)
    gemm8p_k<1, 512, 4><<<512, 512, 0, stream>>>(cur, w1, fc1_b, nullptr, hg, nullptr, M, 1024);
    conv4_k<bf16, bf16, true, 2><<<32 * 8 * 4, 256, 0, stream>>>(hg, 1024, 0, dw_w, dw_b, h2a, 1024, 3);
    gemm8p_k<1, 512, 4><<<512, 512, 0, stream>>>(cur, w1 + (size_t)1024 * 512, fc1_b + 1024, nullptr, hg, nullptr, M, 1024);
    conv4_k<bf16, bf16, true, 2><<<32 * 8 * 4, 256, 0, stream>>>(hg, 1024, 0, dw_w + (size_t)1024 * 9, dw_b + 1024, h2b, 1024, 3);
    // fc2: K=2048 dual-A, 512 blocks (2/CU), fused bias+resid fp32
    gemmfc3_k<<<512, 256, 0, stream>>>(h2a, h2b, w2b, fc2_b, spine, spine, M, 512);
}

// Round 17
// 471.424 us; speedup vs baseline: 1.1143x; 1.1143x over previous
//
#include <hip/hip_runtime.h>
#include <hip/hip_bf16.h>

using bf16 = __hip_bfloat16;
using s16x4 = __attribute__((ext_vector_type(4))) short;
using s16x8 = __attribute__((ext_vector_type(8))) short;
using f32x4 = __attribute__((ext_vector_type(4))) float;

#define DI __device__ __forceinline__

template <int N> DI void wvm() {
    if constexpr (N == 8) asm volatile("s_waitcnt vmcnt(8)" ::: "memory");
    else if constexpr (N == 4) asm volatile("s_waitcnt vmcnt(4)" ::: "memory");
    else if constexpr (N == 2) asm volatile("s_waitcnt vmcnt(2)" ::: "memory");
    else asm volatile("s_waitcnt vmcnt(0)" ::: "memory");
}

DI float b2f(short s) { union { unsigned u; float f; } z; z.u = ((unsigned)(unsigned short)s) << 16; return z.f; }
DI short f2b(float f) { bf16 t = __float2bfloat16(f); return *(short*)&t; }

// fast gelu: tanh form, |err| ~1e-3 absolute, far under threshold
DI float gelu_f(float x) {
    const float t = 0.7978845608f * x * (1.f + 0.044715f * x * x);
    const float e = __expf(2.f * t);
    const float th = 1.f - 2.f / (e + 1.f);
    return 0.5f * x * (1.f + th);
}

DI void ld8(const bf16* p, float* f) {
    s16x8 x = *(const s16x8*)(const void*)p;
#pragma unroll
    for (int c = 0; c < 8; c++) f[c] = b2f(x[c]);
}
DI void ld8(const float* p, float* f) {
    float4 a = *(const float4*)p, b = *(const float4*)(p + 4);
    f[0]=a.x; f[1]=a.y; f[2]=a.z; f[3]=a.w; f[4]=b.x; f[5]=b.y; f[6]=b.z; f[7]=b.w;
}

typedef const __attribute__((address_space(1))) void* gp_t;
typedef __attribute__((address_space(3))) void* lp_t;
DI void gload_lds16(const void* g, void* l) {
    __builtin_amdgcn_global_load_lds((gp_t)g, (lp_t)l, 16, 0, 0);
}

// ---------------- diagnostic ----------------
__global__ void diag_k(float* out, float v) { out[0] = v; }

// ---------------- fp32 -> bf16 weight conversion (8/thread) ----------------
__global__ void f2bf_k(const float* __restrict__ in, bf16* __restrict__ out, int n) {
    int i = (blockIdx.x * 256 + threadIdx.x) * 8;
    if (i >= n) return;
    float f[8];
    ld8(in + i, f);
    s16x8 o;
#pragma unroll
    for (int c = 0; c < 8; c++) o[c] = f2b(f[c]);
    *(s16x8*)(void*)(out + i) = o;
}

// ---------------- depthwise 3x3 conv v4 ----------------
DI void tap10(const float* r, float w0, float w1, float w2, float* acc) {
#pragma unroll
    for (int i = 0; i < 8; i++)
        acc[i] += w0 * r[i] + w1 * r[i + 1] + w2 * r[i + 2];
}

template <typename TI, typename TO, bool RESID, int CPL>
__global__ __launch_bounds__(256) void conv4_k(
    const TI* in, long rs, long coff,
    const float* __restrict__ w, const float* __restrict__ bias,
    TO* out, long ors, int gshift)
{
    constexpr int CH = 64 * CPL;
    constexpr int ECNT = CH / 8;
    __shared__ float buf[2][CH][33];
    const int t = threadIdx.x;
    const int band = blockIdx.x & 3;
    const int cg = (blockIdx.x >> 2) & ((1 << gshift) - 1);
    const int img = blockIdx.x >> (2 + gshift);
    const int y0 = band * 8;

    const int spx = t >> 3;
    const int sce = (t & 7) * ECNT;
    const TI* gsrc = in + ((long)img << 10) * rs + coff + (long)cg * CH + sce;

    const int c = t & 63;
    const int xb = (t >> 6) * 8;

    float wv9[9][CPL], bw[CPL];
#pragma unroll
    for (int p = 0; p < CPL; p++) {
        const int gch = cg * CH + c * CPL + p;
#pragma unroll
        for (int j = 0; j < 9; j++) wv9[j][p] = w[gch * 9 + j];
        bw[p] = bias[gch];
    }

    auto stage = [&](int row) {
        float f[ECNT];
        ld8(gsrc + (long)(row * 32 + spx) * rs, f);
        if constexpr (ECNT == 16) ld8(gsrc + (long)(row * 32 + spx) * rs + 8, f + 8);
        float* d = &buf[row & 1][0][0];
#pragma unroll
        for (int k = 0; k < ECNT; k++) {
            const int ch = sce + k;
            const int rr = (CPL == 2) ? ((ch & 1) * 64 + (ch >> 1)) : ch;
            d[rr * 33 + spx] = f[k];
        }
    };
    auto slice = [&](int row, float r[CPL][10]) {
#pragma unroll
        for (int p = 0; p < CPL; p++) {
            const float* s = &buf[row & 1][c + p * 64][0];
            r[p][0] = (xb == 0) ? 0.f : s[xb - 1];
#pragma unroll
            for (int i = 0; i < 8; i++) r[p][1 + i] = s[xb + i];
            r[p][9] = (xb + 8 >= 32) ? 0.f : s[xb + 8];
        }
    };
    auto zero = [&](float r[CPL][10]) {
#pragma unroll
        for (int p = 0; p < CPL; p++)
#pragma unroll
            for (int i = 0; i < 10; i++) r[p][i] = 0.f;
    };

    float r0[CPL][10], r1[CPL][10], r2[CPL][10];
    if (y0 > 0) stage(y0 - 1);
    __syncthreads();
    if (y0 > 0) slice(y0 - 1, r0); else zero(r0);
    stage(y0);
    __syncthreads();
    slice(y0, r1);

    for (int y = y0; y < y0 + 8; ++y) {
        const int yn = y + 1;
        if (yn <= 31) stage(yn);
        __syncthreads();
        if (yn <= 31) slice(yn, r2); else zero(r2);
        float acc[CPL][8];
#pragma unroll
        for (int p = 0; p < CPL; p++) {
#pragma unroll
            for (int i = 0; i < 8; i++) acc[p][i] = bw[p];
            tap10(r0[p], wv9[0][p], wv9[1][p], wv9[2][p], acc[p]);
            tap10(r1[p], wv9[3][p], wv9[4][p], wv9[5][p], acc[p]);
            tap10(r2[p], wv9[6][p], wv9[7][p], wv9[8][p], acc[p]);
            if (RESID) {
#pragma unroll
                for (int i = 0; i < 8; i++) acc[p][i] += r1[p][i + 1];
            }
        }
        TO* o = out + ((long)(img * 1024 + y * 32 + xb)) * ors + (long)cg * CH + c * CPL;
#pragma unroll
        for (int i = 0; i < 8; i++) {
            if constexpr (CPL == 2 && sizeof(TO) == 2) {
                const unsigned u = (unsigned)(unsigned short)f2b(acc[0][i]) |
                                   ((unsigned)(unsigned short)f2b(acc[1][i]) << 16);
                *(unsigned*)(void*)(o + (long)i * ors) = u;
            } else {
                o[(long)i * ors] = (TO)acc[0][i];
            }
        }
#pragma unroll
        for (int p = 0; p < CPL; p++)
#pragma unroll
            for (int i = 0; i < 10; i++) { r0[p][i] = r1[p][i]; r1[p][i] = r2[p][i]; }
    }
}

// ---------------- LayerNorm over C=512, fp32 in -> bf16 out ----------------
__global__ __launch_bounds__(256) void ln_k(const float* __restrict__ x,
                                            const float* __restrict__ w,
                                            const float* __restrict__ bp,
                                            bf16* __restrict__ out)
{
    const size_t row = blockIdx.x * 4 + (threadIdx.x >> 6);
    const int t = threadIdx.x & 63;
    const float* xr = x + row * 512;
    alignas(16) float v[8];
    *(float4*)&v[0] = *(const float4*)(xr + t * 8);
    *(float4*)&v[4] = *(const float4*)(xr + t * 8 + 4);
    float s = 0.f;
#pragma unroll
    for (int j = 0; j < 8; j++) s += v[j];
#pragma unroll
    for (int mm = 32; mm; mm >>= 1) s += __shfl_xor(s, mm);
    const float mu = s * (1.f / 512.f);
    float q = 0.f;
#pragma unroll
    for (int j = 0; j < 8; j++) { v[j] -= mu; q += v[j] * v[j]; }
#pragma unroll
    for (int mm = 32; mm; mm >>= 1) q += __shfl_xor(q, mm);
    const float rstd = rsqrtf(q * (1.f / 512.f) + 1e-6f);
    alignas(16) float wv[8], bv[8];
    *(float4*)&wv[0] = *(const float4*)(w + t * 8);
    *(float4*)&wv[4] = *(const float4*)(w + t * 8 + 4);
    *(float4*)&bv[0] = *(const float4*)(bp + t * 8);
    *(float4*)&bv[4] = *(const float4*)(bp + t * 8 + 4);
    alignas(16) bf16 o[8];
#pragma unroll
    for (int j = 0; j < 8; j++) o[j] = __float2bfloat16(v[j] * rstd * wv[j] + bv[j]);
    *(uint4*)(out + row * 512 + t * 8) = *(const uint4*)o;
}

// ---------------- 8-phase 256x256 bf16 MFMA GEMM -----------------------------
// BK=64, 8 waves 2Mx4N, 128KB LDS, XCD-swizzled 1D grid. DUAL: A = K-half 0,
// A2 = K-half 1 (lda=K/2). EPI 0: bf16. 1: +bias gelu bf16. 2: +bias +resid fp32.
template <int EPI, int K, int NY, bool DUAL = false>
__global__ __launch_bounds__(512) void gemm8p_k(
    const bf16* __restrict__ A, const bf16* __restrict__ A2,
    const bf16* __restrict__ Bw, const float* __restrict__ bias,
    const float* resid, bf16* __restrict__ outb, float* outf, int M, int Nn)
{
    constexpr int KT = K / 64;
    constexpr int LDA = DUAL ? K / 2 : K;
    __shared__ __align__(16) char lds[131072];
    char* ldsA = lds;
    char* ldsB = lds + 65536;
    const int t = threadIdx.x;
    const int lane = t & 63;
    const int w = t >> 6;
    const int wr = w >> 2, wc = w & 3;
    const int nwg = 128 * NY;
    const int swz = (blockIdx.x & 7) * (nwg >> 3) + (blockIdx.x >> 3);
    const int m0 = (swz / NY) * 256;
    const int n0 = (swz % NY) * 256;
    const int lr = lane & 15, lg = lane >> 4;

    f32x4 acc[8][4] = {};

    const int srow = lane >> 3;
    const int ssrc = 8 * ((lane & 7) ^ srow);

    auto SA = [&](int b, int kt, int h) {
        const bf16* Ab = A;
        int ktl = kt;
        if constexpr (DUAL) { if (kt >= KT / 2) { Ab = A2; ktl = kt - KT / 2; } }
#pragma unroll
        for (int j = 0; j < 2; j++) {
            const int lrow0 = j * 64 + w * 8;
            const int R0 = j * 128 + h * 64 + (lrow0 & 63);
            gload_lds16(Ab + (size_t)(m0 + R0 + srow) * LDA + ktl * 64 + ssrc,
                        ldsA + ((b * 2 + h) * 128 + lrow0) * 128);
        }
    };
    auto SB = [&](int b, int kt, int h) {
#pragma unroll
        for (int j = 0; j < 2; j++) {
            const int lrow0 = j * 64 + w * 8;
            const int R0 = (lrow0 >> 5) * 64 + h * 32 + (lrow0 & 31);
            gload_lds16(Bw + (size_t)(n0 + R0 + srow) * K + kt * 64 + ssrc,
                        ldsB + ((b * 2 + h) * 128 + lrow0) * 128);
        }
    };
    auto RA = [&](int b, int h, int m, int ks) -> s16x8 {
        return *(const s16x8*)(ldsA + ((b * 2 + h) * 128 + wr * 64 + m * 16 + lr) * 128
                               + (((ks * 4 + lg) ^ (lr & 7)) << 4));
    };
    auto RB = [&](int b, int h, int n, int ks) -> s16x8 {
        return *(const s16x8*)(ldsB + ((b * 2 + h) * 128 + wc * 32 + n * 16 + lr) * 128
                               + (((ks * 4 + lg) ^ (lr & 7)) << 4));
    };
    auto MM = [&](int mb, int nb, s16x8 (&a)[2][4], s16x8 (&b)[2][2]) {
#pragma unroll
        for (int ks = 0; ks < 2; ks++)
#pragma unroll
            for (int m = 0; m < 4; m++)
#pragma unroll
                for (int n = 0; n < 2; n++)
                    acc[mb + m][nb + n] =
                        __builtin_amdgcn_mfma_f32_16x16x32_bf16(a[ks][m], b[ks][n], acc[mb + m][nb + n], 0, 0, 0);
    };

    SA(0, 0, 0); SB(0, 0, 0); SA(0, 0, 1); SB(0, 0, 1);
    SA(1, 1, 0); SB(1, 1, 0);
    wvm<8>();
    __builtin_amdgcn_s_barrier();

    s16x8 aLo[2][4], aHi[2][4], bLo[2][2], bHi[2][2];
    auto TILE = [&](int kt) {
        const int b = kt & 1;
#pragma unroll
        for (int ks = 0; ks < 2; ks++) {
#pragma unroll
            for (int m = 0; m < 4; m++) aLo[ks][m] = RA(b, 0, m, ks);
#pragma unroll
            for (int n = 0; n < 2; n++) bLo[ks][n] = RB(b, 0, n, ks);
        }
        if (kt + 1 < KT) SA(b ^ 1, kt + 1, 1);
        __builtin_amdgcn_s_barrier();
        __builtin_amdgcn_s_setprio(1);
        MM(0, 0, aLo, bLo);
        __builtin_amdgcn_s_setprio(0);
        if (kt + 1 < KT) wvm<8>(); else wvm<2>();
        __builtin_amdgcn_s_barrier();
#pragma unroll
        for (int ks = 0; ks < 2; ks++)
#pragma unroll
            for (int m = 0; m < 4; m++) aHi[ks][m] = RA(b, 1, m, ks);
        if (kt + 1 < KT) SB(b ^ 1, kt + 1, 1);
        __builtin_amdgcn_s_barrier();
        __builtin_amdgcn_s_setprio(1);
        MM(4, 0, aHi, bLo);
        __builtin_amdgcn_s_setprio(0);
        if (kt + 1 < KT) wvm<8>(); else wvm<0>();
        __builtin_amdgcn_s_barrier();
#pragma unroll
        for (int ks = 0; ks < 2; ks++)
#pragma unroll
            for (int n = 0; n < 2; n++) bHi[ks][n] = RB(b, 1, n, ks);
        if (kt + 2 < KT) SA(b, kt + 2, 0);
        __builtin_amdgcn_s_barrier();
        __builtin_amdgcn_s_setprio(1);
        MM(4, 2, aHi, bHi);
        __builtin_amdgcn_s_setprio(0);
        __builtin_amdgcn_s_barrier();
        if (kt + 2 < KT) SB(b, kt + 2, 0);
        __builtin_amdgcn_s_barrier();
        __builtin_amdgcn_s_setprio(1);
        MM(0, 2, aLo, bHi);
        __builtin_amdgcn_s_setprio(0);
        if (kt + 2 < KT) { wvm<8>(); __builtin_amdgcn_s_barrier(); }
        else if (kt + 1 < KT) { wvm<4>(); __builtin_amdgcn_s_barrier(); }
    };

    if constexpr (KT <= 8) {
#pragma unroll
        for (int kt = 0; kt < KT; ++kt) TILE(kt);
    } else {
#pragma unroll 2
        for (int kt = 0; kt < KT; ++kt) TILE(kt);
    }

#pragma unroll
    for (int i = 0; i < 8; i++) {
#pragma unroll
        for (int j = 0; j < 4; j++) {
            const int col = n0 + wc * 64 + j * 16 + lr;
            float bcol = 0.f;
            if constexpr (EPI >= 1) bcol = bias[col];
#pragma unroll
            for (int r = 0; r < 4; r++) {
                const int row = m0 + wr * 128 + i * 16 + lg * 4 + r;
                float v = acc[i][j][r] + bcol;
                const size_t idx = (size_t)row * Nn + col;
                if (EPI == 2) outf[idx] = v + resid[idx];
                else outb[idx] = __float2bfloat16(EPI == 1 ? gelu_f(v) : v);
            }
        }
    }
}

// ---------------- ktv v3: token-split MFMA partials (512 blocks, 2/CU) ------
// block = (bh, half): 512 tokens. fp32 partial D[v][k] + csum[k] per block.
__global__ __launch_bounds__(256) void ktv3_k(const bf16* __restrict__ qkv,
                                              float* __restrict__ ktvp,
                                              float* __restrict__ csp)
{
    __shared__ __align__(16) char P[64 * 128];
    __shared__ __align__(16) char Vt[64 * 128];
    __shared__ float csl[64 * 5];
    const int t = threadIdx.x;
    const int bh = blockIdx.x >> 1, half = blockIdx.x & 1;
    const int b = bh >> 3, hh = bh & 7;
    const int lane = t & 63, w = t >> 6;
    const int lr = lane & 15, lg = lane >> 4;

    const int n_r = t >> 2;
    const int k0 = (t & 3) * 16;
    const bf16* kbase = qkv + (size_t)(b * 1024) * 1536 + 512 + hh * 64 + k0;
    const bf16* vbase = kbase + 512;

    const int kq = t & 63, qq = t >> 6;
    float cacc = 0.f;

    f32x4 acc[4] = {};

    for (int n0 = half * 512; n0 < half * 512 + 512; n0 += 64) {
        const uint4 ka = *(const uint4*)(kbase + (size_t)(n0 + n_r) * 1536);
        const uint4 kb2 = *(const uint4*)(kbase + (size_t)(n0 + n_r) * 1536 + 8);
        const uint4 va = *(const uint4*)(vbase + (size_t)(n0 + n_r) * 1536);
        const uint4 vb2 = *(const uint4*)(vbase + (size_t)(n0 + n_r) * 1536 + 8);
        __syncthreads();
        {
            const short* ke = (const short*)&ka;
            const short* ke2 = (const short*)&kb2;
            const short* ve = (const short*)&va;
            const short* ve2 = (const short*)&vb2;
            const int nslot = ((n_r >> 3) << 4);
            const int nbyte = (n_r & 7) * 2;
#pragma unroll
            for (int j = 0; j < 16; j++) {
                const int row = k0 + j;
                const short kv = j < 8 ? ke[j] : ke2[j - 8];
                const short vv = j < 8 ? ve[j] : ve2[j - 8];
                const int off = row * 128 + (nslot ^ ((row & 7) << 4)) + nbyte;
                *(short*)(P + off) = f2b(__expf(b2f(kv)));
                *(short*)(Vt + off) = vv;
            }
        }
        __syncthreads();
        {
            const char* pr = P + kq * 128;
            const int sw = (kq & 7) << 4;
            s16x8 x0 = *(const s16x8*)(pr + (((qq * 2) << 4) ^ sw));
            s16x8 x1 = *(const s16x8*)(pr + (((qq * 2 + 1) << 4) ^ sw));
#pragma unroll
            for (int j = 0; j < 8; j++) cacc += b2f(x0[j]) + b2f(x1[j]);
        }
#pragma unroll
        for (int ks2 = 0; ks2 < 2; ks2++) {
            s16x8 aF = *(const s16x8*)(Vt + (w * 16 + lr) * 128 + (((ks2 * 4 + lg) ^ (lr & 7)) << 4));
            s16x8 bF[4];
#pragma unroll
            for (int j = 0; j < 4; j++)
                bF[j] = *(const s16x8*)(P + (j * 16 + lr) * 128 + (((ks2 * 4 + lg) ^ (lr & 7)) << 4));
#pragma unroll
            for (int j = 0; j < 4; j++)
                acc[j] = __builtin_amdgcn_mfma_f32_16x16x32_bf16(aF, bF[j], acc[j], 0, 0, 0);
        }
    }
    __syncthreads();
    csl[kq * 5 + qq] = cacc;
    __syncthreads();
    if (t < 64) csp[blockIdx.x * 64 + t] = csl[t * 5] + csl[t * 5 + 1] + csl[t * 5 + 2] + csl[t * 5 + 3];

    float* o = ktvp + (size_t)blockIdx.x * 4096;
#pragma unroll
    for (int j = 0; j < 4; j++) {
        const int col = j * 16 + lr;
#pragma unroll
        for (int r = 0; r < 4; r++) {
            const int vrow = w * 16 + lg * 4 + r;
            o[vrow * 64 + col] = acc[j][r];
        }
    }
}

// ---------------- ktv reduce: fold 2 halves, scale, bf16 ktvT ---------------
__global__ __launch_bounds__(256) void ktvred2_k(const float* __restrict__ ktvp,
                                                 const float* __restrict__ csp,
                                                 bf16* __restrict__ ktvT)
{
    const int bh = blockIdx.x;
    const int t = threadIdx.x;
#pragma unroll
    for (int i = 0; i < 16; i++) {
        const int e = t + 256 * i;
        const int col = e & 63;
        const float cs = csp[(bh * 2) * 64 + col] + csp[(bh * 2 + 1) * 64 + col];
        const float val = ktvp[(size_t)(bh * 2) * 4096 + e] + ktvp[(size_t)(bh * 2 + 1) * 4096 + e];
        ktvT[(size_t)bh * 4096 + e] = __float2bfloat16(val * (0.125f / cs));
    }
}

// ---------------- attnout v2: MFMA q@ktvT + fused crpe + residual -----------
__global__ __launch_bounds__(256) void attnout2_k(
    float* xs, const bf16* __restrict__ qkv,
    const bf16* __restrict__ ktvT, const bf16* __restrict__ vc)
{
    __shared__ __align__(16) char qs[256 * 128];
    __shared__ __align__(16) char ks[64 * 128];
    const int t = threadIdx.x;
    const int bid = blockIdx.x;
    const int b = bid >> 5, hh = (bid >> 2) & 7, nc = bid & 3;
    const int n0 = nc * 256;
    const int lane = t & 63, w = t >> 6;
    const int lr = lane & 15, lg = lane >> 4;

    {
        const int r0 = t >> 3, sl = t & 7;
#pragma unroll
        for (int it = 0; it < 8; it++) {
            const int row = it * 32 + r0;
            const uint4 v = *(const uint4*)(qkv + ((size_t)(b * 1024 + n0 + row)) * 1536 + hh * 64 + sl * 8);
            *(uint4*)(qs + row * 128 + ((sl ^ (row & 7)) << 4)) = v;
        }
#pragma unroll
        for (int it = 0; it < 2; it++) {
            const int u = it * 256 + t;
            const int vr = u >> 3, sl2 = u & 7;
            const uint4 vv = *(const uint4*)(ktvT + (size_t)(b * 8 + hh) * 4096 + vr * 64 + sl2 * 8);
            *(uint4*)(ks + vr * 128 + ((sl2 ^ (vr & 7)) << 4)) = vv;
        }
    }
    __syncthreads();

    f32x4 acc[4][4] = {};
    s16x8 aF[2][4], bF[2][4];
#pragma unroll
    for (int ksi = 0; ksi < 2; ksi++) {
#pragma unroll
        for (int m = 0; m < 4; m++) {
            const int row = w * 64 + m * 16 + lr;
            aF[ksi][m] = *(const s16x8*)(qs + row * 128 + (((ksi * 4 + lg) ^ (lr & 7)) << 4));
        }
#pragma unroll
        for (int j = 0; j < 4; j++) {
            const int vr = j * 16 + lr;
            bF[ksi][j] = *(const s16x8*)(ks + vr * 128 + (((ksi * 4 + lg) ^ (lr & 7)) << 4));
        }
    }
#pragma unroll
    for (int ksi = 0; ksi < 2; ksi++)
#pragma unroll
        for (int m = 0; m < 4; m++)
#pragma unroll
            for (int j = 0; j < 4; j++)
                acc[m][j] = __builtin_amdgcn_mfma_f32_16x16x32_bf16(aF[ksi][m], bF[ksi][j], acc[m][j], 0, 0, 0);

#pragma unroll
    for (int m = 0; m < 4; m++) {
#pragma unroll
        for (int j = 0; j < 4; j++) {
#pragma unroll
            for (int r = 0; r < 4; r++) {
                const int lrow = w * 64 + m * 16 + lg * 4 + r;
                const int col = j * 16 + lr;
                const size_t idx = ((size_t)(b * 1024 + n0 + lrow)) * 512 + hh * 64 + col;
                const short qv = *(const short*)(qs + lrow * 128 + ((((col >> 3) ^ (lrow & 7)) << 4)) + (col & 7) * 2);
                xs[idx] = xs[idx] + acc[m][j][r] + b2f(qv) * __bfloat162float(vc[idx]);
            }
        }
    }
}

// ---------------- workspace layout (bytes), full-batch ----------------------
// ktv partials live in the (then-dead) vc region; crpe conv overwrites after.
static constexpr size_t OFF_WQ   = 0;
static constexpr size_t OFF_W1   = 1572864;
static constexpr size_t OFF_W2   = 3670016;
static constexpr size_t OFF_CUR  = 5767168;
static constexpr size_t OFF_H2B  = 5767168;
static constexpr size_t OFF_QKV  = 72876032;
static constexpr size_t OFF_HG   = 72876032;
static constexpr size_t OFF_VC   = 173539328;
static constexpr size_t OFF_KTVP = 173539328;   // fp32 512x4096 = 8MB (in vc region)
static constexpr size_t OFF_CSP  = 181927936;   // fp32 512x64 = 128KB
static constexpr size_t OFF_H2A  = 139984896;
static constexpr size_t OFF_KTV  = 207093760;
static constexpr size_t WS_NEED  = 207618048;   // ~198MB (ws >= 215.5MB confirmed)

extern "C" void kernel_launch(void* const* d_in, const int* in_sizes, int n_in,
                              void* d_out, int out_size, void* d_ws, size_t ws_size,
                              hipStream_t stream)
{
    const float* x     = (const float*)d_in[0];
    const float* cpe_w = (const float*)d_in[1];
    const float* cpe_b = (const float*)d_in[2];
    const float* ln1_w = (const float*)d_in[3];
    const float* ln1_b = (const float*)d_in[4];
    const float* qkv_w = (const float*)d_in[5];
    const float* crpe_w= (const float*)d_in[6];
    const float* crpe_b= (const float*)d_in[7];
    const float* ln2_w = (const float*)d_in[8];
    const float* ln2_b = (const float*)d_in[9];
    const float* fc1_w = (const float*)d_in[10];
    const float* fc1_b = (const float*)d_in[11];
    const float* dw_w  = (const float*)d_in[12];
    const float* dw_b  = (const float*)d_in[13];
    const float* fc2_w = (const float*)d_in[14];
    const float* fc2_b = (const float*)d_in[15];
    float* spine = (float*)d_out;
    char* ws = (char*)d_ws;

    if (ws_size < WS_NEED) {
        diag_k<<<1, 1, 0, stream>>>(spine, (float)ws_size);
        return;
    }

    bf16*  wq   = (bf16*)(ws + OFF_WQ);
    bf16*  w1   = (bf16*)(ws + OFF_W1);
    bf16*  w2b  = (bf16*)(ws + OFF_W2);
    bf16*  cur  = (bf16*)(ws + OFF_CUR);
    bf16*  qkv  = (bf16*)(ws + OFF_QKV);
    bf16*  vc   = (bf16*)(ws + OFF_VC);
    float* ktvp = (float*)(ws + OFF_KTVP);
    float* csp  = (float*)(ws + OFF_CSP);
    bf16*  ktvT = (bf16*)(ws + OFF_KTV);
    bf16*  hg   = (bf16*)(ws + OFF_HG);
    bf16*  h2a  = (bf16*)(ws + OFF_H2A);
    bf16*  h2b  = (bf16*)(ws + OFF_H2B);

    // weights -> bf16 (w2 native [512][2048])
    f2bf_k<<<(1536 * 512 / 8 + 255) / 256, 256, 0, stream>>>(qkv_w, wq, 1536 * 512);
    f2bf_k<<<(2048 * 512 / 8 + 255) / 256, 256, 0, stream>>>(fc1_w, w1, 2048 * 512);
    f2bf_k<<<(2048 * 512 / 8 + 255) / 256, 256, 0, stream>>>(fc2_w, w2b, 512 * 2048);

    // CPE (fp32, 64-ch groups): spine = x + dwconv(x) + cpe_b
    conv4_k<float, float, true, 1><<<32 * 8 * 4, 256, 0, stream>>>(x, 512, 0, cpe_w, cpe_b, spine, 512, 3);

    const int M = 32768;
    // LN1
    ln_k<<<M / 4, 256, 0, stream>>>(spine, ln1_w, ln1_b, cur);
    // qkv: 768 blocks (XCD-swizzled)
    gemm8p_k<0, 512, 6><<<768, 512, 0, stream>>>(cur, nullptr, wq, nullptr, nullptr, qkv, nullptr, M, 1536);
    // ktv: token-split partials (512 blocks, 2/CU) + reduce
    ktv3_k<<<512, 256, 0, stream>>>(qkv, ktvp, csp);
    ktvred2_k<<<256, 256, 0, stream>>>(ktvp, csp, ktvT);
    // crpe conv on v (overwrites ktv partial region)
    conv4_k<bf16, bf16, false, 2><<<32 * 4 * 4, 256, 0, stream>>>(qkv, 1536, 1024, crpe_w, crpe_b, vc, 512, 2);
    // attention output (MFMA), in place on spine
    attnout2_k<<<32 * 8 * 4, 256, 0, stream>>>(spine, qkv, ktvT, vc);
    // LN2
    ln_k<<<M / 4, 256, 0, stream>>>(spine, ln2_w, ln2_b, cur);

    // MLP: fc1(h0)->conv(h0)->fc1(h1)->conv(h1)->fc2(dual, single pass)
    gemm8p_k<1, 512, 4><<<512, 512, 0, stream>>>(cur, nullptr, w1, fc1_b, nullptr, hg, nullptr, M, 1024);
    conv4_k<bf16, bf16, true, 2><<<32 * 8 * 4, 256, 0, stream>>>(hg, 1024, 0, dw_w, dw_b, h2a, 1024, 3);
    gemm8p_k<1, 512, 4><<<512, 512, 0, stream>>>(cur, nullptr, w1 + (size_t)1024 * 512, fc1_b + 1024, nullptr, hg, nullptr, M, 1024);
    conv4_k<bf16, bf16, true, 2><<<32 * 8 * 4, 256, 0, stream>>>(hg, 1024, 0, dw_w + (size_t)1024 * 9, dw_b + 1024, h2b, 1024, 3);
    // fc2: K=2048 dual-A 8-phase, 256 blocks; +bias +resid fp32 in place
    gemm8p_k<2, 2048, 2, true><<<256, 512, 0, stream>>>(h2a, h2b, w2b, fc2_b, spine, nullptr, spine, M, 512);
}

// Round 19
// 466.586 us; speedup vs baseline: 1.1259x; 1.0104x over previous
//
#include <hip/hip_runtime.h>
#include <hip/hip_bf16.h>

using bf16 = __hip_bfloat16;
using s16x4 = __attribute__((ext_vector_type(4))) short;
using s16x8 = __attribute__((ext_vector_type(8))) short;
using f32x4 = __attribute__((ext_vector_type(4))) float;

#define DI __device__ __forceinline__

template <int N> DI void wvm() {
    if constexpr (N == 8) asm volatile("s_waitcnt vmcnt(8)" ::: "memory");
    else if constexpr (N == 4) asm volatile("s_waitcnt vmcnt(4)" ::: "memory");
    else if constexpr (N == 2) asm volatile("s_waitcnt vmcnt(2)" ::: "memory");
    else if constexpr (N == 1) asm volatile("s_waitcnt vmcnt(1)" ::: "memory");
    else asm volatile("s_waitcnt vmcnt(0)" ::: "memory");
}

DI float b2f(short s) { union { unsigned u; float f; } z; z.u = ((unsigned)(unsigned short)s) << 16; return z.f; }
DI short f2b(float f) { bf16 t = __float2bfloat16(f); return *(short*)&t; }

// fast gelu: tanh form, |err| ~1e-3 absolute, far under threshold
DI float gelu_f(float x) {
    const float t = 0.7978845608f * x * (1.f + 0.044715f * x * x);
    const float e = __expf(2.f * t);
    const float th = 1.f - 2.f / (e + 1.f);
    return 0.5f * x * (1.f + th);
}

DI void ld8(const bf16* p, float* f) {
    s16x8 x = *(const s16x8*)(const void*)p;
#pragma unroll
    for (int c = 0; c < 8; c++) f[c] = b2f(x[c]);
}
DI void ld8(const float* p, float* f) {
    float4 a = *(const float4*)p, b = *(const float4*)(p + 4);
    f[0]=a.x; f[1]=a.y; f[2]=a.z; f[3]=a.w; f[4]=b.x; f[5]=b.y; f[6]=b.z; f[7]=b.w;
}

typedef const __attribute__((address_space(1))) void* gp_t;
typedef __attribute__((address_space(3))) void* lp_t;
DI void gload_lds16(const void* g, void* l) {
    __builtin_amdgcn_global_load_lds((gp_t)g, (lp_t)l, 16, 0, 0);
}

// ---------------- diagnostic ----------------
__global__ void diag_k(float* out, float v) { out[0] = v; }

// ---------------- fp32 -> bf16 weight conversion (8/thread) ----------------
__global__ void f2bf_k(const float* __restrict__ in, bf16* __restrict__ out, int n) {
    int i = (blockIdx.x * 256 + threadIdx.x) * 8;
    if (i >= n) return;
    float f[8];
    ld8(in + i, f);
    s16x8 o;
#pragma unroll
    for (int c = 0; c < 8; c++) o[c] = f2b(f[c]);
    *(s16x8*)(void*)(out + i) = o;
}

// ---------------- depthwise 3x3 conv v4 ----------------
DI void tap10(const float* r, float w0, float w1, float w2, float* acc) {
#pragma unroll
    for (int i = 0; i < 8; i++)
        acc[i] += w0 * r[i] + w1 * r[i + 1] + w2 * r[i + 2];
}

template <typename TI, typename TO, bool RESID, int CPL>
__global__ __launch_bounds__(256) void conv4_k(
    const TI* in, long rs, long coff,
    const float* __restrict__ w, const float* __restrict__ bias,
    TO* out, long ors, int gshift)
{
    constexpr int CH = 64 * CPL;
    constexpr int ECNT = CH / 8;
    __shared__ float buf[2][CH][33];
    const int t = threadIdx.x;
    const int band = blockIdx.x & 3;
    const int cg = (blockIdx.x >> 2) & ((1 << gshift) - 1);
    const int img = blockIdx.x >> (2 + gshift);
    const int y0 = band * 8;

    const int spx = t >> 3;
    const int sce = (t & 7) * ECNT;
    const TI* gsrc = in + ((long)img << 10) * rs + coff + (long)cg * CH + sce;

    const int c = t & 63;
    const int xb = (t >> 6) * 8;

    float wv9[9][CPL], bw[CPL];
#pragma unroll
    for (int p = 0; p < CPL; p++) {
        const int gch = cg * CH + c * CPL + p;
#pragma unroll
        for (int j = 0; j < 9; j++) wv9[j][p] = w[gch * 9 + j];
        bw[p] = bias[gch];
    }

    auto stage = [&](int row) {
        float f[ECNT];
        ld8(gsrc + (long)(row * 32 + spx) * rs, f);
        if constexpr (ECNT == 16) ld8(gsrc + (long)(row * 32 + spx) * rs + 8, f + 8);
        float* d = &buf[row & 1][0][0];
#pragma unroll
        for (int k = 0; k < ECNT; k++) {
            const int ch = sce + k;
            const int rr = (CPL == 2) ? ((ch & 1) * 64 + (ch >> 1)) : ch;
            d[rr * 33 + spx] = f[k];
        }
    };
    auto slice = [&](int row, float r[CPL][10]) {
#pragma unroll
        for (int p = 0; p < CPL; p++) {
            const float* s = &buf[row & 1][c + p * 64][0];
            r[p][0] = (xb == 0) ? 0.f : s[xb - 1];
#pragma unroll
            for (int i = 0; i < 8; i++) r[p][1 + i] = s[xb + i];
            r[p][9] = (xb + 8 >= 32) ? 0.f : s[xb + 8];
        }
    };
    auto zero = [&](float r[CPL][10]) {
#pragma unroll
        for (int p = 0; p < CPL; p++)
#pragma unroll
            for (int i = 0; i < 10; i++) r[p][i] = 0.f;
    };

    float r0[CPL][10], r1[CPL][10], r2[CPL][10];
    if (y0 > 0) stage(y0 - 1);
    __syncthreads();
    if (y0 > 0) slice(y0 - 1, r0); else zero(r0);
    stage(y0);
    __syncthreads();
    slice(y0, r1);

    for (int y = y0; y < y0 + 8; ++y) {
        const int yn = y + 1;
        if (yn <= 31) stage(yn);
        __syncthreads();
        if (yn <= 31) slice(yn, r2); else zero(r2);
        float acc[CPL][8];
#pragma unroll
        for (int p = 0; p < CPL; p++) {
#pragma unroll
            for (int i = 0; i < 8; i++) acc[p][i] = bw[p];
            tap10(r0[p], wv9[0][p], wv9[1][p], wv9[2][p], acc[p]);
            tap10(r1[p], wv9[3][p], wv9[4][p], wv9[5][p], acc[p]);
            tap10(r2[p], wv9[6][p], wv9[7][p], wv9[8][p], acc[p]);
            if (RESID) {
#pragma unroll
                for (int i = 0; i < 8; i++) acc[p][i] += r1[p][i + 1];
            }
        }
        TO* o = out + ((long)(img * 1024 + y * 32 + xb)) * ors + (long)cg * CH + c * CPL;
#pragma unroll
        for (int i = 0; i < 8; i++) {
            if constexpr (CPL == 2 && sizeof(TO) == 2) {
                const unsigned u = (unsigned)(unsigned short)f2b(acc[0][i]) |
                                   ((unsigned)(unsigned short)f2b(acc[1][i]) << 16);
                *(unsigned*)(void*)(o + (long)i * ors) = u;
            } else {
                o[(long)i * ors] = (TO)acc[0][i];
            }
        }
#pragma unroll
        for (int p = 0; p < CPL; p++)
#pragma unroll
            for (int i = 0; i < 10; i++) { r0[p][i] = r1[p][i]; r1[p][i] = r2[p][i]; }
    }
}

// ---------------- LayerNorm over C=512, fp32 in -> bf16 out ----------------
__global__ __launch_bounds__(256) void ln_k(const float* __restrict__ x,
                                            const float* __restrict__ w,
                                            const float* __restrict__ bp,
                                            bf16* __restrict__ out)
{
    const size_t row = blockIdx.x * 4 + (threadIdx.x >> 6);
    const int t = threadIdx.x & 63;
    const float* xr = x + row * 512;
    alignas(16) float v[8];
    *(float4*)&v[0] = *(const float4*)(xr + t * 8);
    *(float4*)&v[4] = *(const float4*)(xr + t * 8 + 4);
    float s = 0.f;
#pragma unroll
    for (int j = 0; j < 8; j++) s += v[j];
#pragma unroll
    for (int mm = 32; mm; mm >>= 1) s += __shfl_xor(s, mm);
    const float mu = s * (1.f / 512.f);
    float q = 0.f;
#pragma unroll
    for (int j = 0; j < 8; j++) { v[j] -= mu; q += v[j] * v[j]; }
#pragma unroll
    for (int mm = 32; mm; mm >>= 1) q += __shfl_xor(q, mm);
    const float rstd = rsqrtf(q * (1.f / 512.f) + 1e-6f);
    alignas(16) float wv[8], bv[8];
    *(float4*)&wv[0] = *(const float4*)(w + t * 8);
    *(float4*)&wv[4] = *(const float4*)(w + t * 8 + 4);
    *(float4*)&bv[0] = *(const float4*)(bp + t * 8);
    *(float4*)&bv[4] = *(const float4*)(bp + t * 8 + 4);
    alignas(16) bf16 o[8];
#pragma unroll
    for (int j = 0; j < 8; j++) o[j] = __float2bfloat16(v[j] * rstd * wv[j] + bv[j]);
    *(uint4*)(out + row * 512 + t * 8) = *(const uint4*)o;
}

// ---------------- 8-phase 256x256 bf16 MFMA GEMM -----------------------------
// BK=64, 8 waves 2Mx4N, 128KB LDS, XCD-swizzled 1D grid.
// EPI 0: bf16. 1: +bias gelu bf16.
template <int EPI, int K, int NY>
__global__ __launch_bounds__(512) void gemm8p_k(
    const bf16* __restrict__ A, const bf16* __restrict__ Bw,
    const float* __restrict__ bias, bf16* __restrict__ outb, int M, int Nn)
{
    constexpr int KT = K / 64;
    __shared__ __align__(16) char lds[131072];
    char* ldsA = lds;
    char* ldsB = lds + 65536;
    const int t = threadIdx.x;
    const int lane = t & 63;
    const int w = t >> 6;
    const int wr = w >> 2, wc = w & 3;
    const int nwg = 128 * NY;
    const int swz = (blockIdx.x & 7) * (nwg >> 3) + (blockIdx.x >> 3);
    const int m0 = (swz / NY) * 256;
    const int n0 = (swz % NY) * 256;
    const int lr = lane & 15, lg = lane >> 4;

    f32x4 acc[8][4] = {};

    const int srow = lane >> 3;
    const int ssrc = 8 * ((lane & 7) ^ srow);

    auto SA = [&](int b, int kt, int h) {
#pragma unroll
        for (int j = 0; j < 2; j++) {
            const int lrow0 = j * 64 + w * 8;
            const int R0 = j * 128 + h * 64 + (lrow0 & 63);
            gload_lds16(A + (size_t)(m0 + R0 + srow) * K + kt * 64 + ssrc,
                        ldsA + ((b * 2 + h) * 128 + lrow0) * 128);
        }
    };
    auto SB = [&](int b, int kt, int h) {
#pragma unroll
        for (int j = 0; j < 2; j++) {
            const int lrow0 = j * 64 + w * 8;
            const int R0 = (lrow0 >> 5) * 64 + h * 32 + (lrow0 & 31);
            gload_lds16(Bw + (size_t)(n0 + R0 + srow) * K + kt * 64 + ssrc,
                        ldsB + ((b * 2 + h) * 128 + lrow0) * 128);
        }
    };
    auto RA = [&](int b, int h, int m, int ks) -> s16x8 {
        return *(const s16x8*)(ldsA + ((b * 2 + h) * 128 + wr * 64 + m * 16 + lr) * 128
                               + (((ks * 4 + lg) ^ (lr & 7)) << 4));
    };
    auto RB = [&](int b, int h, int n, int ks) -> s16x8 {
        return *(const s16x8*)(ldsB + ((b * 2 + h) * 128 + wc * 32 + n * 16 + lr) * 128
                               + (((ks * 4 + lg) ^ (lr & 7)) << 4));
    };
    auto MM = [&](int mb, int nb, s16x8 (&a)[2][4], s16x8 (&b)[2][2]) {
#pragma unroll
        for (int ks = 0; ks < 2; ks++)
#pragma unroll
            for (int m = 0; m < 4; m++)
#pragma unroll
                for (int n = 0; n < 2; n++)
                    acc[mb + m][nb + n] =
                        __builtin_amdgcn_mfma_f32_16x16x32_bf16(a[ks][m], b[ks][n], acc[mb + m][nb + n], 0, 0, 0);
    };

    SA(0, 0, 0); SB(0, 0, 0); SA(0, 0, 1); SB(0, 0, 1);
    SA(1, 1, 0); SB(1, 1, 0);
    wvm<8>();
    __builtin_amdgcn_s_barrier();

    s16x8 aLo[2][4], aHi[2][4], bLo[2][2], bHi[2][2];
    auto TILE = [&](int kt) {
        const int b = kt & 1;
#pragma unroll
        for (int ks = 0; ks < 2; ks++) {
#pragma unroll
            for (int m = 0; m < 4; m++) aLo[ks][m] = RA(b, 0, m, ks);
#pragma unroll
            for (int n = 0; n < 2; n++) bLo[ks][n] = RB(b, 0, n, ks);
        }
        if (kt + 1 < KT) SA(b ^ 1, kt + 1, 1);
        __builtin_amdgcn_s_barrier();
        __builtin_amdgcn_s_setprio(1);
        MM(0, 0, aLo, bLo);
        __builtin_amdgcn_s_setprio(0);
        if (kt + 1 < KT) wvm<8>(); else wvm<2>();
        __builtin_amdgcn_s_barrier();
#pragma unroll
        for (int ks = 0; ks < 2; ks++)
#pragma unroll
            for (int m = 0; m < 4; m++) aHi[ks][m] = RA(b, 1, m, ks);
        if (kt + 1 < KT) SB(b ^ 1, kt + 1, 1);
        __builtin_amdgcn_s_barrier();
        __builtin_amdgcn_s_setprio(1);
        MM(4, 0, aHi, bLo);
        __builtin_amdgcn_s_setprio(0);
        if (kt + 1 < KT) wvm<8>(); else wvm<0>();
        __builtin_amdgcn_s_barrier();
#pragma unroll
        for (int ks = 0; ks < 2; ks++)
#pragma unroll
            for (int n = 0; n < 2; n++) bHi[ks][n] = RB(b, 1, n, ks);
        if (kt + 2 < KT) SA(b, kt + 2, 0);
        __builtin_amdgcn_s_barrier();
        __builtin_amdgcn_s_setprio(1);
        MM(4, 2, aHi, bHi);
        __builtin_amdgcn_s_setprio(0);
        __builtin_amdgcn_s_barrier();
        if (kt + 2 < KT) SB(b, kt + 2, 0);
        __builtin_amdgcn_s_barrier();
        __builtin_amdgcn_s_setprio(1);
        MM(0, 2, aLo, bHi);
        __builtin_amdgcn_s_setprio(0);
        if (kt + 2 < KT) { wvm<8>(); __builtin_amdgcn_s_barrier(); }
        else if (kt + 1 < KT) { wvm<4>(); __builtin_amdgcn_s_barrier(); }
    };

#pragma unroll
    for (int kt = 0; kt < KT; ++kt) TILE(kt);

#pragma unroll
    for (int i = 0; i < 8; i++) {
#pragma unroll
        for (int j = 0; j < 4; j++) {
            const int col = n0 + wc * 64 + j * 16 + lr;
            float bcol = 0.f;
            if constexpr (EPI >= 1) bcol = bias[col];
#pragma unroll
            for (int r = 0; r < 4; r++) {
                const int row = m0 + wr * 128 + i * 16 + lg * 4 + r;
                float v = acc[i][j][r] + bcol;
                const size_t idx = (size_t)row * Nn + col;
                outb[idx] = __float2bfloat16(EPI == 1 ? gelu_f(v) : v);
            }
        }
    }
}

// ---------------- fc2: 8-phase schedule at BM=BN=128, 64KB LDS, 2 blocks/CU -
// Same counted-vmcnt phase structure as gemm8p scaled by 1/2 (1 stage instr
// per wave per half; steady vmcnt(4), tails 1/0/2). Dual-A K=2048 (lda=1024).
// 8 waves 2Mx4N: wave out = 64x32. Grid 1024 (=2 rounds of 2/CU), XCD swizzle.
__global__ __launch_bounds__(512) void gemm8ps_k(
    const bf16* __restrict__ A, const bf16* __restrict__ A2,
    const bf16* __restrict__ Bw, const float* __restrict__ bias,
    const float* resid, float* outf, int M, int Nn)
{
    constexpr int KT = 32;            // K=2048 / BK=64
    __shared__ __align__(16) char lds[65536];
    char* ldsA = lds;                 // [2buf][2half][64 rows][128B]
    char* ldsB = lds + 32768;
    const int t = threadIdx.x;
    const int lane = t & 63;
    const int w = t >> 6;
    const int wr = w >> 2, wc = w & 3;
    const int swz = (blockIdx.x & 7) * 128 + (blockIdx.x >> 3);   // nwg=1024
    const int m0 = (swz >> 2) * 128;
    const int n0 = (swz & 3) * 128;
    const int lr = lane & 15, lg = lane >> 4;

    f32x4 acc[4][2] = {};             // [h_m*2+m][h_n]

    const int srow = lane >> 3;
    const int ssrc = 8 * ((lane & 7) ^ srow);
    const int lrow0 = w * 8;

    auto SA = [&](int b, int kt, int h) {
        const bf16* Ab = (kt < 16) ? A : A2;
        const int ktl = (kt < 16) ? kt : kt - 16;
        const int R0 = h * 64 + lrow0;
        gload_lds16(Ab + (size_t)(m0 + R0 + srow) * 1024 + ktl * 64 + ssrc,
                    ldsA + ((b * 2 + h) * 64 + lrow0) * 128);
    };
    auto SB = [&](int b, int kt, int h) {
        const int R0 = (lrow0 >> 4) * 32 + h * 16 + (lrow0 & 15);
        gload_lds16(Bw + (size_t)(n0 + R0 + srow) * 2048 + kt * 64 + ssrc,
                    ldsB + ((b * 2 + h) * 64 + lrow0) * 128);
    };
    auto RA = [&](int b, int h, int m, int ks) -> s16x8 {
        return *(const s16x8*)(ldsA + ((b * 2 + h) * 64 + wr * 32 + m * 16 + lr) * 128
                               + (((ks * 4 + lg) ^ (lr & 7)) << 4));
    };
    auto RB = [&](int b, int h, int ks) -> s16x8 {
        return *(const s16x8*)(ldsB + ((b * 2 + h) * 64 + wc * 16 + lr) * 128
                               + (((ks * 4 + lg) ^ (lr & 7)) << 4));
    };
    auto MM = [&](int hm, int hn, s16x8 (&a)[2][2], s16x8 (&bb)[2]) {
#pragma unroll
        for (int ks = 0; ks < 2; ks++)
#pragma unroll
            for (int m = 0; m < 2; m++)
                acc[hm * 2 + m][hn] =
                    __builtin_amdgcn_mfma_f32_16x16x32_bf16(a[ks][m], bb[ks], acc[hm * 2 + m][hn], 0, 0, 0);
    };

    SA(0, 0, 0); SB(0, 0, 0); SA(0, 0, 1); SB(0, 0, 1);
    SA(1, 1, 0); SB(1, 1, 0);
    wvm<4>();
    __builtin_amdgcn_s_barrier();

    s16x8 aLo[2][2], aHi[2][2], bLo[2], bHi[2];
#pragma unroll 2
    for (int kt = 0; kt < KT; ++kt) {
        const int b = kt & 1;
        // phase 0: (M-lo x N-lo); stage A-hi(kt+1)
#pragma unroll
        for (int ks = 0; ks < 2; ks++) {
#pragma unroll
            for (int m = 0; m < 2; m++) aLo[ks][m] = RA(b, 0, m, ks);
            bLo[ks] = RB(b, 0, ks);
        }
        if (kt + 1 < KT) SA(b ^ 1, kt + 1, 1);
        __builtin_amdgcn_s_barrier();
        __builtin_amdgcn_s_setprio(1);
        MM(0, 0, aLo, bLo);
        __builtin_amdgcn_s_setprio(0);
        if (kt + 1 < KT) wvm<4>(); else wvm<1>();
        __builtin_amdgcn_s_barrier();
        // phase 1: (M-hi x N-lo); stage B-hi(kt+1)
#pragma unroll
        for (int ks = 0; ks < 2; ks++)
#pragma unroll
            for (int m = 0; m < 2; m++) aHi[ks][m] = RA(b, 1, m, ks);
        if (kt + 1 < KT) SB(b ^ 1, kt + 1, 1);
        __builtin_amdgcn_s_barrier();
        __builtin_amdgcn_s_setprio(1);
        MM(1, 0, aHi, bLo);
        __builtin_amdgcn_s_setprio(0);
        if (kt + 1 < KT) wvm<4>(); else wvm<0>();
        __builtin_amdgcn_s_barrier();
        // phase 2: (M-hi x N-hi); stage A-lo(kt+2)
#pragma unroll
        for (int ks = 0; ks < 2; ks++) bHi[ks] = RB(b, 1, ks);
        if (kt + 2 < KT) SA(b, kt + 2, 0);
        __builtin_amdgcn_s_barrier();
        __builtin_amdgcn_s_setprio(1);
        MM(1, 1, aHi, bHi);
        __builtin_amdgcn_s_setprio(0);
        __builtin_amdgcn_s_barrier();
        // phase 3: (M-lo x N-hi); stage B-lo(kt+2)
        if (kt + 2 < KT) SB(b, kt + 2, 0);
        __builtin_amdgcn_s_barrier();
        __builtin_amdgcn_s_setprio(1);
        MM(0, 1, aLo, bHi);
        __builtin_amdgcn_s_setprio(0);
        if (kt + 2 < KT) { wvm<4>(); __builtin_amdgcn_s_barrier(); }
        else if (kt + 1 < KT) { wvm<2>(); __builtin_amdgcn_s_barrier(); }
    }

#pragma unroll
    for (int mf = 0; mf < 4; mf++) {
#pragma unroll
        for (int nf = 0; nf < 2; nf++) {
            const int col = n0 + wc * 32 + nf * 16 + lr;
            const float bcol = bias[col];
#pragma unroll
            for (int r = 0; r < 4; r++) {
                const int row = m0 + (mf >> 1) * 64 + wr * 32 + (mf & 1) * 16 + lg * 4 + r;
                const size_t idx = (size_t)row * Nn + col;
                outf[idx] = acc[mf][nf][r] + bcol + resid[idx];
            }
        }
    }
}

// ---------------- ktv v3: token-split MFMA partials (512 blocks, 2/CU) ------
__global__ __launch_bounds__(256) void ktv3_k(const bf16* __restrict__ qkv,
                                              float* __restrict__ ktvp,
                                              float* __restrict__ csp)
{
    __shared__ __align__(16) char P[64 * 128];
    __shared__ __align__(16) char Vt[64 * 128];
    __shared__ float csl[64 * 5];
    const int t = threadIdx.x;
    const int bh = blockIdx.x >> 1, half = blockIdx.x & 1;
    const int b = bh >> 3, hh = bh & 7;
    const int lane = t & 63, w = t >> 6;
    const int lr = lane & 15, lg = lane >> 4;

    const int n_r = t >> 2;
    const int k0 = (t & 3) * 16;
    const bf16* kbase = qkv + (size_t)(b * 1024) * 1536 + 512 + hh * 64 + k0;
    const bf16* vbase = kbase + 512;

    const int kq = t & 63, qq = t >> 6;
    float cacc = 0.f;

    f32x4 acc[4] = {};

    for (int n0 = half * 512; n0 < half * 512 + 512; n0 += 64) {
        const uint4 ka = *(const uint4*)(kbase + (size_t)(n0 + n_r) * 1536);
        const uint4 kb2 = *(const uint4*)(kbase + (size_t)(n0 + n_r) * 1536 + 8);
        const uint4 va = *(const uint4*)(vbase + (size_t)(n0 + n_r) * 1536);
        const uint4 vb2 = *(const uint4*)(vbase + (size_t)(n0 + n_r) * 1536 + 8);
        __syncthreads();
        {
            const short* ke = (const short*)&ka;
            const short* ke2 = (const short*)&kb2;
            const short* ve = (const short*)&va;
            const short* ve2 = (const short*)&vb2;
            const int nslot = ((n_r >> 3) << 4);
            const int nbyte = (n_r & 7) * 2;
#pragma unroll
            for (int j = 0; j < 16; j++) {
                const int row = k0 + j;
                const short kv = j < 8 ? ke[j] : ke2[j - 8];
                const short vv = j < 8 ? ve[j] : ve2[j - 8];
                const int off = row * 128 + (nslot ^ ((row & 7) << 4)) + nbyte;
                *(short*)(P + off) = f2b(__expf(b2f(kv)));
                *(short*)(Vt + off) = vv;
            }
        }
        __syncthreads();
        {
            const char* pr = P + kq * 128;
            const int sw = (kq & 7) << 4;
            s16x8 x0 = *(const s16x8*)(pr + (((qq * 2) << 4) ^ sw));
            s16x8 x1 = *(const s16x8*)(pr + (((qq * 2 + 1) << 4) ^ sw));
#pragma unroll
            for (int j = 0; j < 8; j++) cacc += b2f(x0[j]) + b2f(x1[j]);
        }
#pragma unroll
        for (int ks2 = 0; ks2 < 2; ks2++) {
            s16x8 aF = *(const s16x8*)(Vt + (w * 16 + lr) * 128 + (((ks2 * 4 + lg) ^ (lr & 7)) << 4));
            s16x8 bF[4];
#pragma unroll
            for (int j = 0; j < 4; j++)
                bF[j] = *(const s16x8*)(P + (j * 16 + lr) * 128 + (((ks2 * 4 + lg) ^ (lr & 7)) << 4));
#pragma unroll
            for (int j = 0; j < 4; j++)
                acc[j] = __builtin_amdgcn_mfma_f32_16x16x32_bf16(aF, bF[j], acc[j], 0, 0, 0);
        }
    }
    __syncthreads();
    csl[kq * 5 + qq] = cacc;
    __syncthreads();
    if (t < 64) csp[blockIdx.x * 64 + t] = csl[t * 5] + csl[t * 5 + 1] + csl[t * 5 + 2] + csl[t * 5 + 3];

    float* o = ktvp + (size_t)blockIdx.x * 4096;
#pragma unroll
    for (int j = 0; j < 4; j++) {
        const int col = j * 16 + lr;
#pragma unroll
        for (int r = 0; r < 4; r++) {
            const int vrow = w * 16 + lg * 4 + r;
            o[vrow * 64 + col] = acc[j][r];
        }
    }
}

// ---------------- ktv reduce: fold 2 halves, scale, bf16 ktvT ---------------
__global__ __launch_bounds__(256) void ktvred2_k(const float* __restrict__ ktvp,
                                                 const float* __restrict__ csp,
                                                 bf16* __restrict__ ktvT)
{
    const int bh = blockIdx.x;
    const int t = threadIdx.x;
#pragma unroll
    for (int i = 0; i < 16; i++) {
        const int e = t + 256 * i;
        const int col = e & 63;
        const float cs = csp[(bh * 2) * 64 + col] + csp[(bh * 2 + 1) * 64 + col];
        const float val = ktvp[(size_t)(bh * 2) * 4096 + e] + ktvp[(size_t)(bh * 2 + 1) * 4096 + e];
        ktvT[(size_t)bh * 4096 + e] = __float2bfloat16(val * (0.125f / cs));
    }
}

// ---------------- attnout v2: MFMA q@ktvT + fused crpe + residual -----------
__global__ __launch_bounds__(256) void attnout2_k(
    float* xs, const bf16* __restrict__ qkv,
    const bf16* __restrict__ ktvT, const bf16* __restrict__ vc)
{
    __shared__ __align__(16) char qs[256 * 128];
    __shared__ __align__(16) char ks[64 * 128];
    const int t = threadIdx.x;
    const int bid = blockIdx.x;
    const int b = bid >> 5, hh = (bid >> 2) & 7, nc = bid & 3;
    const int n0 = nc * 256;
    const int lane = t & 63, w = t >> 6;
    const int lr = lane & 15, lg = lane >> 4;

    {
        const int r0 = t >> 3, sl = t & 7;
#pragma unroll
        for (int it = 0; it < 8; it++) {
            const int row = it * 32 + r0;
            const uint4 v = *(const uint4*)(qkv + ((size_t)(b * 1024 + n0 + row)) * 1536 + hh * 64 + sl * 8);
            *(uint4*)(qs + row * 128 + ((sl ^ (row & 7)) << 4)) = v;
        }
#pragma unroll
        for (int it = 0; it < 2; it++) {
            const int u = it * 256 + t;
            const int vr = u >> 3, sl2 = u & 7;
            const uint4 vv = *(const uint4*)(ktvT + (size_t)(b * 8 + hh) * 4096 + vr * 64 + sl2 * 8);
            *(uint4*)(ks + vr * 128 + ((sl2 ^ (vr & 7)) << 4)) = vv;
        }
    }
    __syncthreads();

    f32x4 acc[4][4] = {};
    s16x8 aF[2][4], bF[2][4];
#pragma unroll
    for (int ksi = 0; ksi < 2; ksi++) {
#pragma unroll
        for (int m = 0; m < 4; m++) {
            const int row = w * 64 + m * 16 + lr;
            aF[ksi][m] = *(const s16x8*)(qs + row * 128 + (((ksi * 4 + lg) ^ (lr & 7)) << 4));
        }
#pragma unroll
        for (int j = 0; j < 4; j++) {
            const int vr = j * 16 + lr;
            bF[ksi][j] = *(const s16x8*)(ks + vr * 128 + (((ksi * 4 + lg) ^ (lr & 7)) << 4));
        }
    }
#pragma unroll
    for (int ksi = 0; ksi < 2; ksi++)
#pragma unroll
        for (int m = 0; m < 4; m++)
#pragma unroll
            for (int j = 0; j < 4; j++)
                acc[m][j] = __builtin_amdgcn_mfma_f32_16x16x32_bf16(aF[ksi][m], bF[ksi][j], acc[m][j], 0, 0, 0);

#pragma unroll
    for (int m = 0; m < 4; m++) {
#pragma unroll
        for (int j = 0; j < 4; j++) {
#pragma unroll
            for (int r = 0; r < 4; r++) {
                const int lrow = w * 64 + m * 16 + lg * 4 + r;
                const int col = j * 16 + lr;
                const size_t idx = ((size_t)(b * 1024 + n0 + lrow)) * 512 + hh * 64 + col;
                const short qv = *(const short*)(qs + lrow * 128 + ((((col >> 3) ^ (lrow & 7)) << 4)) + (col & 7) * 2);
                xs[idx] = xs[idx] + acc[m][j][r] + b2f(qv) * __bfloat162float(vc[idx]);
            }
        }
    }
}

// ---------------- workspace layout (bytes), full-batch ----------------------
static constexpr size_t OFF_WQ   = 0;
static constexpr size_t OFF_W1   = 1572864;
static constexpr size_t OFF_W2   = 3670016;
static constexpr size_t OFF_CUR  = 5767168;
static constexpr size_t OFF_H2B  = 5767168;     // over cur: write ONLY after last cur read
static constexpr size_t OFF_QKV  = 72876032;
static constexpr size_t OFF_HG   = 72876032;
static constexpr size_t OFF_VC   = 173539328;
static constexpr size_t OFF_KTVP = 173539328;   // fp32 512x4096 (in vc region)
static constexpr size_t OFF_CSP  = 181927936;
static constexpr size_t OFF_H2A  = 139984896;
static constexpr size_t OFF_KTV  = 207093760;
static constexpr size_t WS_NEED  = 207618048;   // ~198MB (ws >= 215.5MB confirmed)

extern "C" void kernel_launch(void* const* d_in, const int* in_sizes, int n_in,
                              void* d_out, int out_size, void* d_ws, size_t ws_size,
                              hipStream_t stream)
{
    const float* x     = (const float*)d_in[0];
    const float* cpe_w = (const float*)d_in[1];
    const float* cpe_b = (const float*)d_in[2];
    const float* ln1_w = (const float*)d_in[3];
    const float* ln1_b = (const float*)d_in[4];
    const float* qkv_w = (const float*)d_in[5];
    const float* crpe_w= (const float*)d_in[6];
    const float* crpe_b= (const float*)d_in[7];
    const float* ln2_w = (const float*)d_in[8];
    const float* ln2_b = (const float*)d_in[9];
    const float* fc1_w = (const float*)d_in[10];
    const float* fc1_b = (const float*)d_in[11];
    const float* dw_w  = (const float*)d_in[12];
    const float* dw_b  = (const float*)d_in[13];
    const float* fc2_w = (const float*)d_in[14];
    const float* fc2_b = (const float*)d_in[15];
    float* spine = (float*)d_out;
    char* ws = (char*)d_ws;

    if (ws_size < WS_NEED) {
        diag_k<<<1, 1, 0, stream>>>(spine, (float)ws_size);
        return;
    }

    bf16*  wq   = (bf16*)(ws + OFF_WQ);
    bf16*  w1   = (bf16*)(ws + OFF_W1);
    bf16*  w2b  = (bf16*)(ws + OFF_W2);
    bf16*  cur  = (bf16*)(ws + OFF_CUR);
    bf16*  qkv  = (bf16*)(ws + OFF_QKV);
    bf16*  vc   = (bf16*)(ws + OFF_VC);
    float* ktvp = (float*)(ws + OFF_KTVP);
    float* csp  = (float*)(ws + OFF_CSP);
    bf16*  ktvT = (bf16*)(ws + OFF_KTV);
    bf16*  hg   = (bf16*)(ws + OFF_HG);
    bf16*  h2a  = (bf16*)(ws + OFF_H2A);
    bf16*  h2b  = (bf16*)(ws + OFF_H2B);

    // weights -> bf16 (w2 native [512][2048])
    f2bf_k<<<(1536 * 512 / 8 + 255) / 256, 256, 0, stream>>>(qkv_w, wq, 1536 * 512);
    f2bf_k<<<(2048 * 512 / 8 + 255) / 256, 256, 0, stream>>>(fc1_w, w1, 2048 * 512);
    f2bf_k<<<(2048 * 512 / 8 + 255) / 256, 256, 0, stream>>>(fc2_w, w2b, 512 * 2048);

    // CPE (fp32, 64-ch groups): spine = x + dwconv(x) + cpe_b
    conv4_k<float, float, true, 1><<<32 * 8 * 4, 256, 0, stream>>>(x, 512, 0, cpe_w, cpe_b, spine, 512, 3);

    const int M = 32768;
    // LN1
    ln_k<<<M / 4, 256, 0, stream>>>(spine, ln1_w, ln1_b, cur);
    // qkv: 768 blocks (XCD-swizzled)
    gemm8p_k<0, 512, 6><<<768, 512, 0, stream>>>(cur, wq, nullptr, qkv, M, 1536);
    // ktv: token-split partials + reduce
    ktv3_k<<<512, 256, 0, stream>>>(qkv, ktvp, csp);
    ktvred2_k<<<256, 256, 0, stream>>>(ktvp, csp, ktvT);
    // crpe conv on v (overwrites ktv partial region)
    conv4_k<bf16, bf16, false, 2><<<32 * 4 * 4, 256, 0, stream>>>(qkv, 1536, 1024, crpe_w, crpe_b, vc, 512, 2);
    // attention output (MFMA), in place on spine
    attnout2_k<<<32 * 8 * 4, 256, 0, stream>>>(spine, qkv, ktvT, vc);
    // LN2
    ln_k<<<M / 4, 256, 0, stream>>>(spine, ln2_w, ln2_b, cur);

    // MLP (lifetime-correct order): h0 -> h2a first; h2b (over cur) LAST
    gemm8p_k<1, 512, 4><<<512, 512, 0, stream>>>(cur, w1, fc1_b, hg, M, 1024);
    conv4_k<bf16, bf16, true, 2><<<32 * 8 * 4, 256, 0, stream>>>(hg, 1024, 0, dw_w, dw_b, h2a, 1024, 3);
    gemm8p_k<1, 512, 4><<<512, 512, 0, stream>>>(cur, w1 + (size_t)1024 * 512, fc1_b + 1024, hg, M, 1024);
    conv4_k<bf16, bf16, true, 2><<<32 * 8 * 4, 256, 0, stream>>>(hg, 1024, 0, dw_w + (size_t)1024 * 9, dw_b + 1024, h2b, 1024, 3);
    // fc2: K=2048 dual-A, BM=BN=128, 1024 blocks (2/CU), counted-vmcnt 8-phase
    gemm8ps_k<<<1024, 512, 0, stream>>>(h2a, h2b, w2b, fc2_b, spine, spine, M, 512);
}

// Round 20
// 465.622 us; speedup vs baseline: 1.1282x; 1.0021x over previous
//
#include <hip/hip_runtime.h>
#include <hip/hip_bf16.h>

using bf16 = __hip_bfloat16;
using s16x4 = __attribute__((ext_vector_type(4))) short;
using s16x8 = __attribute__((ext_vector_type(8))) short;
using f32x4 = __attribute__((ext_vector_type(4))) float;

#define DI __device__ __forceinline__

template <int N> DI void wvm() {
    if constexpr (N == 8) asm volatile("s_waitcnt vmcnt(8)" ::: "memory");
    else if constexpr (N == 4) asm volatile("s_waitcnt vmcnt(4)" ::: "memory");
    else if constexpr (N == 2) asm volatile("s_waitcnt vmcnt(2)" ::: "memory");
    else if constexpr (N == 1) asm volatile("s_waitcnt vmcnt(1)" ::: "memory");
    else asm volatile("s_waitcnt vmcnt(0)" ::: "memory");
}

DI float b2f(short s) { union { unsigned u; float f; } z; z.u = ((unsigned)(unsigned short)s) << 16; return z.f; }
DI short f2b(float f) { bf16 t = __float2bfloat16(f); return *(short*)&t; }

// fast gelu: tanh form, |err| ~1e-3 absolute, far under threshold
DI float gelu_f(float x) {
    const float t = 0.7978845608f * x * (1.f + 0.044715f * x * x);
    const float e = __expf(2.f * t);
    const float th = 1.f - 2.f / (e + 1.f);
    return 0.5f * x * (1.f + th);
}

DI void ld8(const bf16* p, float* f) {
    s16x8 x = *(const s16x8*)(const void*)p;
#pragma unroll
    for (int c = 0; c < 8; c++) f[c] = b2f(x[c]);
}
DI void ld8(const float* p, float* f) {
    float4 a = *(const float4*)p, b = *(const float4*)(p + 4);
    f[0]=a.x; f[1]=a.y; f[2]=a.z; f[3]=a.w; f[4]=b.x; f[5]=b.y; f[6]=b.z; f[7]=b.w;
}

typedef const __attribute__((address_space(1))) void* gp_t;
typedef __attribute__((address_space(3))) void* lp_t;
DI void gload_lds16(const void* g, void* l) {
    __builtin_amdgcn_global_load_lds((gp_t)g, (lp_t)l, 16, 0, 0);
}

// ---------------- diagnostic ----------------
__global__ void diag_k(float* out, float v) { out[0] = v; }

// ---------------- fp32 -> bf16 weight conversion (8/thread) ----------------
__global__ void f2bf_k(const float* __restrict__ in, bf16* __restrict__ out, int n) {
    int i = (blockIdx.x * 256 + threadIdx.x) * 8;
    if (i >= n) return;
    float f[8];
    ld8(in + i, f);
    s16x8 o;
#pragma unroll
    for (int c = 0; c < 8; c++) o[c] = f2b(f[c]);
    *(s16x8*)(void*)(out + i) = o;
}

// ---------------- depthwise 3x3 conv v4 ----------------
DI void tap10(const float* r, float w0, float w1, float w2, float* acc) {
#pragma unroll
    for (int i = 0; i < 8; i++)
        acc[i] += w0 * r[i] + w1 * r[i + 1] + w2 * r[i + 2];
}

template <typename TI, typename TO, bool RESID, int CPL>
__global__ __launch_bounds__(256) void conv4_k(
    const TI* in, long rs, long coff,
    const float* __restrict__ w, const float* __restrict__ bias,
    TO* out, long ors, int gshift)
{
    constexpr int CH = 64 * CPL;
    constexpr int ECNT = CH / 8;
    __shared__ float buf[2][CH][33];
    const int t = threadIdx.x;
    const int band = blockIdx.x & 3;
    const int cg = (blockIdx.x >> 2) & ((1 << gshift) - 1);
    const int img = blockIdx.x >> (2 + gshift);
    const int y0 = band * 8;

    const int spx = t >> 3;
    const int sce = (t & 7) * ECNT;
    const TI* gsrc = in + ((long)img << 10) * rs + coff + (long)cg * CH + sce;

    const int c = t & 63;
    const int xb = (t >> 6) * 8;

    float wv9[9][CPL], bw[CPL];
#pragma unroll
    for (int p = 0; p < CPL; p++) {
        const int gch = cg * CH + c * CPL + p;
#pragma unroll
        for (int j = 0; j < 9; j++) wv9[j][p] = w[gch * 9 + j];
        bw[p] = bias[gch];
    }

    auto stage = [&](int row) {
        float f[ECNT];
        ld8(gsrc + (long)(row * 32 + spx) * rs, f);
        if constexpr (ECNT == 16) ld8(gsrc + (long)(row * 32 + spx) * rs + 8, f + 8);
        float* d = &buf[row & 1][0][0];
#pragma unroll
        for (int k = 0; k < ECNT; k++) {
            const int ch = sce + k;
            const int rr = (CPL == 2) ? ((ch & 1) * 64 + (ch >> 1)) : ch;
            d[rr * 33 + spx] = f[k];
        }
    };
    auto slice = [&](int row, float r[CPL][10]) {
#pragma unroll
        for (int p = 0; p < CPL; p++) {
            const float* s = &buf[row & 1][c + p * 64][0];
            r[p][0] = (xb == 0) ? 0.f : s[xb - 1];
#pragma unroll
            for (int i = 0; i < 8; i++) r[p][1 + i] = s[xb + i];
            r[p][9] = (xb + 8 >= 32) ? 0.f : s[xb + 8];
        }
    };
    auto zero = [&](float r[CPL][10]) {
#pragma unroll
        for (int p = 0; p < CPL; p++)
#pragma unroll
            for (int i = 0; i < 10; i++) r[p][i] = 0.f;
    };

    float r0[CPL][10], r1[CPL][10], r2[CPL][10];
    if (y0 > 0) stage(y0 - 1);
    __syncthreads();
    if (y0 > 0) slice(y0 - 1, r0); else zero(r0);
    stage(y0);
    __syncthreads();
    slice(y0, r1);

    for (int y = y0; y < y0 + 8; ++y) {
        const int yn = y + 1;
        if (yn <= 31) stage(yn);
        __syncthreads();
        if (yn <= 31) slice(yn, r2); else zero(r2);
        float acc[CPL][8];
#pragma unroll
        for (int p = 0; p < CPL; p++) {
#pragma unroll
            for (int i = 0; i < 8; i++) acc[p][i] = bw[p];
            tap10(r0[p], wv9[0][p], wv9[1][p], wv9[2][p], acc[p]);
            tap10(r1[p], wv9[3][p], wv9[4][p], wv9[5][p], acc[p]);
            tap10(r2[p], wv9[6][p], wv9[7][p], wv9[8][p], acc[p]);
            if (RESID) {
#pragma unroll
                for (int i = 0; i < 8; i++) acc[p][i] += r1[p][i + 1];
            }
        }
        TO* o = out + ((long)(img * 1024 + y * 32 + xb)) * ors + (long)cg * CH + c * CPL;
#pragma unroll
        for (int i = 0; i < 8; i++) {
            if constexpr (CPL == 2 && sizeof(TO) == 2) {
                const unsigned u = (unsigned)(unsigned short)f2b(acc[0][i]) |
                                   ((unsigned)(unsigned short)f2b(acc[1][i]) << 16);
                *(unsigned*)(void*)(o + (long)i * ors) = u;
            } else {
                o[(long)i * ors] = (TO)acc[0][i];
            }
        }
#pragma unroll
        for (int p = 0; p < CPL; p++)
#pragma unroll
            for (int i = 0; i < 10; i++) { r0[p][i] = r1[p][i]; r1[p][i] = r2[p][i]; }
    }
}

// ---------------- LayerNorm over C=512, fp32 in -> bf16 out ----------------
__global__ __launch_bounds__(256) void ln_k(const float* __restrict__ x,
                                            const float* __restrict__ w,
                                            const float* __restrict__ bp,
                                            bf16* __restrict__ out)
{
    const size_t row = blockIdx.x * 4 + (threadIdx.x >> 6);
    const int t = threadIdx.x & 63;
    const float* xr = x + row * 512;
    alignas(16) float v[8];
    *(float4*)&v[0] = *(const float4*)(xr + t * 8);
    *(float4*)&v[4] = *(const float4*)(xr + t * 8 + 4);
    float s = 0.f;
#pragma unroll
    for (int j = 0; j < 8; j++) s += v[j];
#pragma unroll
    for (int mm = 32; mm; mm >>= 1) s += __shfl_xor(s, mm);
    const float mu = s * (1.f / 512.f);
    float q = 0.f;
#pragma unroll
    for (int j = 0; j < 8; j++) { v[j] -= mu; q += v[j] * v[j]; }
#pragma unroll
    for (int mm = 32; mm; mm >>= 1) q += __shfl_xor(q, mm);
    const float rstd = rsqrtf(q * (1.f / 512.f) + 1e-6f);
    alignas(16) float wv[8], bv[8];
    *(float4*)&wv[0] = *(const float4*)(w + t * 8);
    *(float4*)&wv[4] = *(const float4*)(w + t * 8 + 4);
    *(float4*)&bv[0] = *(const float4*)(bp + t * 8);
    *(float4*)&bv[4] = *(const float4*)(bp + t * 8 + 4);
    alignas(16) bf16 o[8];
#pragma unroll
    for (int j = 0; j < 8; j++) o[j] = __float2bfloat16(v[j] * rstd * wv[j] + bv[j]);
    *(uint4*)(out + row * 512 + t * 8) = *(const uint4*)o;
}

// ---------------- 8-phase 256x256 bf16 MFMA GEMM (qkv) ----------------------
template <int EPI, int K, int NY>
__global__ __launch_bounds__(512) void gemm8p_k(
    const bf16* __restrict__ A, const bf16* __restrict__ Bw,
    const float* __restrict__ bias, bf16* __restrict__ outb, int M, int Nn)
{
    constexpr int KT = K / 64;
    __shared__ __align__(16) char lds[131072];
    char* ldsA = lds;
    char* ldsB = lds + 65536;
    const int t = threadIdx.x;
    const int lane = t & 63;
    const int w = t >> 6;
    const int wr = w >> 2, wc = w & 3;
    const int nwg = 128 * NY;
    const int swz = (blockIdx.x & 7) * (nwg >> 3) + (blockIdx.x >> 3);
    const int m0 = (swz / NY) * 256;
    const int n0 = (swz % NY) * 256;
    const int lr = lane & 15, lg = lane >> 4;

    f32x4 acc[8][4] = {};

    const int srow = lane >> 3;
    const int ssrc = 8 * ((lane & 7) ^ srow);

    auto SA = [&](int b, int kt, int h) {
#pragma unroll
        for (int j = 0; j < 2; j++) {
            const int lrow0 = j * 64 + w * 8;
            const int R0 = j * 128 + h * 64 + (lrow0 & 63);
            gload_lds16(A + (size_t)(m0 + R0 + srow) * K + kt * 64 + ssrc,
                        ldsA + ((b * 2 + h) * 128 + lrow0) * 128);
        }
    };
    auto SB = [&](int b, int kt, int h) {
#pragma unroll
        for (int j = 0; j < 2; j++) {
            const int lrow0 = j * 64 + w * 8;
            const int R0 = (lrow0 >> 5) * 64 + h * 32 + (lrow0 & 31);
            gload_lds16(Bw + (size_t)(n0 + R0 + srow) * K + kt * 64 + ssrc,
                        ldsB + ((b * 2 + h) * 128 + lrow0) * 128);
        }
    };
    auto RA = [&](int b, int h, int m, int ks) -> s16x8 {
        return *(const s16x8*)(ldsA + ((b * 2 + h) * 128 + wr * 64 + m * 16 + lr) * 128
                               + (((ks * 4 + lg) ^ (lr & 7)) << 4));
    };
    auto RB = [&](int b, int h, int n, int ks) -> s16x8 {
        return *(const s16x8*)(ldsB + ((b * 2 + h) * 128 + wc * 32 + n * 16 + lr) * 128
                               + (((ks * 4 + lg) ^ (lr & 7)) << 4));
    };
    auto MM = [&](int mb, int nb, s16x8 (&a)[2][4], s16x8 (&b)[2][2]) {
#pragma unroll
        for (int ks = 0; ks < 2; ks++)
#pragma unroll
            for (int m = 0; m < 4; m++)
#pragma unroll
                for (int n = 0; n < 2; n++)
                    acc[mb + m][nb + n] =
                        __builtin_amdgcn_mfma_f32_16x16x32_bf16(a[ks][m], b[ks][n], acc[mb + m][nb + n], 0, 0, 0);
    };

    SA(0, 0, 0); SB(0, 0, 0); SA(0, 0, 1); SB(0, 0, 1);
    SA(1, 1, 0); SB(1, 1, 0);
    wvm<8>();
    __builtin_amdgcn_s_barrier();

    s16x8 aLo[2][4], aHi[2][4], bLo[2][2], bHi[2][2];
    auto TILE = [&](int kt) {
        const int b = kt & 1;
#pragma unroll
        for (int ks = 0; ks < 2; ks++) {
#pragma unroll
            for (int m = 0; m < 4; m++) aLo[ks][m] = RA(b, 0, m, ks);
#pragma unroll
            for (int n = 0; n < 2; n++) bLo[ks][n] = RB(b, 0, n, ks);
        }
        if (kt + 1 < KT) SA(b ^ 1, kt + 1, 1);
        __builtin_amdgcn_s_barrier();
        __builtin_amdgcn_s_setprio(1);
        MM(0, 0, aLo, bLo);
        __builtin_amdgcn_s_setprio(0);
        if (kt + 1 < KT) wvm<8>(); else wvm<2>();
        __builtin_amdgcn_s_barrier();
#pragma unroll
        for (int ks = 0; ks < 2; ks++)
#pragma unroll
            for (int m = 0; m < 4; m++) aHi[ks][m] = RA(b, 1, m, ks);
        if (kt + 1 < KT) SB(b ^ 1, kt + 1, 1);
        __builtin_amdgcn_s_barrier();
        __builtin_amdgcn_s_setprio(1);
        MM(4, 0, aHi, bLo);
        __builtin_amdgcn_s_setprio(0);
        if (kt + 1 < KT) wvm<8>(); else wvm<0>();
        __builtin_amdgcn_s_barrier();
#pragma unroll
        for (int ks = 0; ks < 2; ks++)
#pragma unroll
            for (int n = 0; n < 2; n++) bHi[ks][n] = RB(b, 1, n, ks);
        if (kt + 2 < KT) SA(b, kt + 2, 0);
        __builtin_amdgcn_s_barrier();
        __builtin_amdgcn_s_setprio(1);
        MM(4, 2, aHi, bHi);
        __builtin_amdgcn_s_setprio(0);
        __builtin_amdgcn_s_barrier();
        if (kt + 2 < KT) SB(b, kt + 2, 0);
        __builtin_amdgcn_s_barrier();
        __builtin_amdgcn_s_setprio(1);
        MM(0, 2, aLo, bHi);
        __builtin_amdgcn_s_setprio(0);
        if (kt + 2 < KT) { wvm<8>(); __builtin_amdgcn_s_barrier(); }
        else if (kt + 1 < KT) { wvm<4>(); __builtin_amdgcn_s_barrier(); }
    };

#pragma unroll
    for (int kt = 0; kt < KT; ++kt) TILE(kt);

#pragma unroll
    for (int i = 0; i < 8; i++) {
#pragma unroll
        for (int j = 0; j < 4; j++) {
            const int col = n0 + wc * 64 + j * 16 + lr;
            float bcol = 0.f;
            if constexpr (EPI >= 1) bcol = bias[col];
#pragma unroll
            for (int r = 0; r < 4; r++) {
                const int row = m0 + wr * 128 + i * 16 + lg * 4 + r;
                float v = acc[i][j][r] + bcol;
                const size_t idx = (size_t)row * Nn + col;
                outb[idx] = __float2bfloat16(EPI == 1 ? gelu_f(v) : v);
            }
        }
    }
}

// ---------------- small-tile 8-phase GEMM: BM=BN=128, 64KB LDS, 2/CU --------
// Counted-vmcnt schedule (steady 4, tails 1/0/2). DUAL: A=K-half0, A2=K-half1.
// EPI 0: bf16. 1: +bias gelu bf16. 2: +bias +resid fp32 (in-place ok).
template <int EPI, int K, int NY, bool DUAL>
__global__ __launch_bounds__(512) void gemm8ps_k(
    const bf16* __restrict__ A, const bf16* __restrict__ A2,
    const bf16* __restrict__ Bw, const float* __restrict__ bias,
    const float* resid, bf16* __restrict__ outb, float* outf, int M, int Nn)
{
    constexpr int KT = K / 64;
    constexpr int LDA = DUAL ? K / 2 : K;
    __shared__ __align__(16) char lds[65536];
    char* ldsA = lds;
    char* ldsB = lds + 32768;
    const int t = threadIdx.x;
    const int lane = t & 63;
    const int w = t >> 6;
    const int wr = w >> 2, wc = w & 3;
    const int nwg = gridDim.x;
    const int swz = (blockIdx.x & 7) * (nwg >> 3) + (blockIdx.x >> 3);
    const int m0 = (swz / NY) * 128;
    const int n0 = (swz % NY) * 128;
    const int lr = lane & 15, lg = lane >> 4;

    f32x4 acc[4][2] = {};

    const int srow = lane >> 3;
    const int ssrc = 8 * ((lane & 7) ^ srow);
    const int lrow0 = w * 8;

    auto SA = [&](int b, int kt, int h) {
        const bf16* Ab = A;
        int ktl = kt;
        if constexpr (DUAL) { if (kt >= KT / 2) { Ab = A2; ktl = kt - KT / 2; } }
        const int R0 = h * 64 + lrow0;
        gload_lds16(Ab + (size_t)(m0 + R0 + srow) * LDA + ktl * 64 + ssrc,
                    ldsA + ((b * 2 + h) * 64 + lrow0) * 128);
    };
    auto SB = [&](int b, int kt, int h) {
        const int R0 = (lrow0 >> 4) * 32 + h * 16 + (lrow0 & 15);
        gload_lds16(Bw + (size_t)(n0 + R0 + srow) * K + kt * 64 + ssrc,
                    ldsB + ((b * 2 + h) * 64 + lrow0) * 128);
    };
    auto RA = [&](int b, int h, int m, int ks) -> s16x8 {
        return *(const s16x8*)(ldsA + ((b * 2 + h) * 64 + wr * 32 + m * 16 + lr) * 128
                               + (((ks * 4 + lg) ^ (lr & 7)) << 4));
    };
    auto RB = [&](int b, int h, int ks) -> s16x8 {
        return *(const s16x8*)(ldsB + ((b * 2 + h) * 64 + wc * 16 + lr) * 128
                               + (((ks * 4 + lg) ^ (lr & 7)) << 4));
    };
    auto MM = [&](int hm, int hn, s16x8 (&a)[2][2], s16x8 (&bb)[2]) {
#pragma unroll
        for (int ks = 0; ks < 2; ks++)
#pragma unroll
            for (int m = 0; m < 2; m++)
                acc[hm * 2 + m][hn] =
                    __builtin_amdgcn_mfma_f32_16x16x32_bf16(a[ks][m], bb[ks], acc[hm * 2 + m][hn], 0, 0, 0);
    };

    SA(0, 0, 0); SB(0, 0, 0); SA(0, 0, 1); SB(0, 0, 1);
    SA(1, 1, 0); SB(1, 1, 0);
    wvm<4>();
    __builtin_amdgcn_s_barrier();

    s16x8 aLo[2][2], aHi[2][2], bLo[2], bHi[2];
#pragma unroll 2
    for (int kt = 0; kt < KT; ++kt) {
        const int b = kt & 1;
        // phase 0: (M-lo x N-lo); stage A-hi(kt+1)
#pragma unroll
        for (int ks = 0; ks < 2; ks++) {
#pragma unroll
            for (int m = 0; m < 2; m++) aLo[ks][m] = RA(b, 0, m, ks);
            bLo[ks] = RB(b, 0, ks);
        }
        if (kt + 1 < KT) SA(b ^ 1, kt + 1, 1);
        __builtin_amdgcn_s_barrier();
        __builtin_amdgcn_s_setprio(1);
        MM(0, 0, aLo, bLo);
        __builtin_amdgcn_s_setprio(0);
        if (kt + 1 < KT) wvm<4>(); else wvm<1>();
        __builtin_amdgcn_s_barrier();
        // phase 1: (M-hi x N-lo); stage B-hi(kt+1)
#pragma unroll
        for (int ks = 0; ks < 2; ks++)
#pragma unroll
            for (int m = 0; m < 2; m++) aHi[ks][m] = RA(b, 1, m, ks);
        if (kt + 1 < KT) SB(b ^ 1, kt + 1, 1);
        __builtin_amdgcn_s_barrier();
        __builtin_amdgcn_s_setprio(1);
        MM(1, 0, aHi, bLo);
        __builtin_amdgcn_s_setprio(0);
        if (kt + 1 < KT) wvm<4>(); else wvm<0>();
        __builtin_amdgcn_s_barrier();
        // phase 2: (M-hi x N-hi); stage A-lo(kt+2)
#pragma unroll
        for (int ks = 0; ks < 2; ks++) bHi[ks] = RB(b, 1, ks);
        if (kt + 2 < KT) SA(b, kt + 2, 0);
        __builtin_amdgcn_s_barrier();
        __builtin_amdgcn_s_setprio(1);
        MM(1, 1, aHi, bHi);
        __builtin_amdgcn_s_setprio(0);
        __builtin_amdgcn_s_barrier();
        // phase 3: (M-lo x N-hi); stage B-lo(kt+2)
        if (kt + 2 < KT) SB(b, kt + 2, 0);
        __builtin_amdgcn_s_barrier();
        __builtin_amdgcn_s_setprio(1);
        MM(0, 1, aLo, bHi);
        __builtin_amdgcn_s_setprio(0);
        if (kt + 2 < KT) { wvm<4>(); __builtin_amdgcn_s_barrier(); }
        else if (kt + 1 < KT) { wvm<2>(); __builtin_amdgcn_s_barrier(); }
    }

#pragma unroll
    for (int mf = 0; mf < 4; mf++) {
#pragma unroll
        for (int nf = 0; nf < 2; nf++) {
            const int col = n0 + wc * 32 + nf * 16 + lr;
            float bcol = 0.f;
            if constexpr (EPI >= 1) bcol = bias[col];
#pragma unroll
            for (int r = 0; r < 4; r++) {
                const int row = m0 + (mf >> 1) * 64 + wr * 32 + (mf & 1) * 16 + lg * 4 + r;
                float v = acc[mf][nf][r] + bcol;
                const size_t idx = (size_t)row * Nn + col;
                if (EPI == 2) outf[idx] = v + resid[idx];
                else outb[idx] = __float2bfloat16(EPI == 1 ? gelu_f(v) : v);
            }
        }
    }
}

// ---------------- ktv v3: token-split MFMA partials (512 blocks, 2/CU) ------
__global__ __launch_bounds__(256) void ktv3_k(const bf16* __restrict__ qkv,
                                              float* __restrict__ ktvp,
                                              float* __restrict__ csp)
{
    __shared__ __align__(16) char P[64 * 128];
    __shared__ __align__(16) char Vt[64 * 128];
    __shared__ float csl[64 * 5];
    const int t = threadIdx.x;
    const int bh = blockIdx.x >> 1, half = blockIdx.x & 1;
    const int b = bh >> 3, hh = bh & 7;
    const int lane = t & 63, w = t >> 6;
    const int lr = lane & 15, lg = lane >> 4;

    const int n_r = t >> 2;
    const int k0 = (t & 3) * 16;
    const bf16* kbase = qkv + (size_t)(b * 1024) * 1536 + 512 + hh * 64 + k0;
    const bf16* vbase = kbase + 512;

    const int kq = t & 63, qq = t >> 6;
    float cacc = 0.f;

    f32x4 acc[4] = {};

    for (int n0 = half * 512; n0 < half * 512 + 512; n0 += 64) {
        const uint4 ka = *(const uint4*)(kbase + (size_t)(n0 + n_r) * 1536);
        const uint4 kb2 = *(const uint4*)(kbase + (size_t)(n0 + n_r) * 1536 + 8);
        const uint4 va = *(const uint4*)(vbase + (size_t)(n0 + n_r) * 1536);
        const uint4 vb2 = *(const uint4*)(vbase + (size_t)(n0 + n_r) * 1536 + 8);
        __syncthreads();
        {
            const short* ke = (const short*)&ka;
            const short* ke2 = (const short*)&kb2;
            const short* ve = (const short*)&va;
            const short* ve2 = (const short*)&vb2;
            const int nslot = ((n_r >> 3) << 4);
            const int nbyte = (n_r & 7) * 2;
#pragma unroll
            for (int j = 0; j < 16; j++) {
                const int row = k0 + j;
                const short kv = j < 8 ? ke[j] : ke2[j - 8];
                const short vv = j < 8 ? ve[j] : ve2[j - 8];
                const int off = row * 128 + (nslot ^ ((row & 7) << 4)) + nbyte;
                *(short*)(P + off) = f2b(__expf(b2f(kv)));
                *(short*)(Vt + off) = vv;
            }
        }
        __syncthreads();
        {
            const char* pr = P + kq * 128;
            const int sw = (kq & 7) << 4;
            s16x8 x0 = *(const s16x8*)(pr + (((qq * 2) << 4) ^ sw));
            s16x8 x1 = *(const s16x8*)(pr + (((qq * 2 + 1) << 4) ^ sw));
#pragma unroll
            for (int j = 0; j < 8; j++) cacc += b2f(x0[j]) + b2f(x1[j]);
        }
#pragma unroll
        for (int ks2 = 0; ks2 < 2; ks2++) {
            s16x8 aF = *(const s16x8*)(Vt + (w * 16 + lr) * 128 + (((ks2 * 4 + lg) ^ (lr & 7)) << 4));
            s16x8 bF[4];
#pragma unroll
            for (int j = 0; j < 4; j++)
                bF[j] = *(const s16x8*)(P + (j * 16 + lr) * 128 + (((ks2 * 4 + lg) ^ (lr & 7)) << 4));
#pragma unroll
            for (int j = 0; j < 4; j++)
                acc[j] = __builtin_amdgcn_mfma_f32_16x16x32_bf16(aF, bF[j], acc[j], 0, 0, 0);
        }
    }
    __syncthreads();
    csl[kq * 5 + qq] = cacc;
    __syncthreads();
    if (t < 64) csp[blockIdx.x * 64 + t] = csl[t * 5] + csl[t * 5 + 1] + csl[t * 5 + 2] + csl[t * 5 + 3];

    float* o = ktvp + (size_t)blockIdx.x * 4096;
#pragma unroll
    for (int j = 0; j < 4; j++) {
        const int col = j * 16 + lr;
#pragma unroll
        for (int r = 0; r < 4; r++) {
            const int vrow = w * 16 + lg * 4 + r;
            o[vrow * 64 + col] = acc[j][r];
        }
    }
}

// ---------------- attnout v3: fused ktv-reduce + MFMA q@ktvT + crpe + resid --
__global__ __launch_bounds__(256) void attnout3_k(
    float* xs, const bf16* __restrict__ qkv,
    const float* __restrict__ ktvp, const float* __restrict__ csp,
    const bf16* __restrict__ vc)
{
    __shared__ __align__(16) char qs[256 * 128];
    __shared__ __align__(16) char ks[64 * 128];
    const int t = threadIdx.x;
    const int bid = blockIdx.x;
    const int b = bid >> 5, hh = (bid >> 2) & 7, nc = bid & 3;
    const int bh = b * 8 + hh;
    const int n0 = nc * 256;
    const int lane = t & 63, w = t >> 6;
    const int lr = lane & 15, lg = lane >> 4;

    {
        const int r0 = t >> 3, sl = t & 7;
#pragma unroll
        for (int it = 0; it < 8; it++) {
            const int row = it * 32 + r0;
            const uint4 v = *(const uint4*)(qkv + ((size_t)(b * 1024 + n0 + row)) * 1536 + hh * 64 + sl * 8);
            *(uint4*)(qs + row * 128 + ((sl ^ (row & 7)) << 4)) = v;
        }
        // fused reduce: ktvT[vr][col] = (p0+p1) * 0.125/(cs0+cs1), bf16, swizzled
#pragma unroll
        for (int it = 0; it < 2; it++) {
            const int u = it * 256 + t;
            const int vr = u >> 3, sl2 = u & 7;
            const float* p0 = ktvp + (size_t)(bh * 2) * 4096 + vr * 64 + sl2 * 8;
            const float* p1 = p0 + 4096;
            s16x8 o;
#pragma unroll
            for (int j = 0; j < 8; j++) {
                const int col = sl2 * 8 + j;
                const float cs = csp[(bh * 2) * 64 + col] + csp[(bh * 2 + 1) * 64 + col];
                o[j] = f2b((p0[j] + p1[j]) * (0.125f / cs));
            }
            *(s16x8*)(void*)(ks + vr * 128 + ((sl2 ^ (vr & 7)) << 4)) = o;
        }
    }
    __syncthreads();

    f32x4 acc[4][4] = {};
    s16x8 aF[2][4], bF[2][4];
#pragma unroll
    for (int ksi = 0; ksi < 2; ksi++) {
#pragma unroll
        for (int m = 0; m < 4; m++) {
            const int row = w * 64 + m * 16 + lr;
            aF[ksi][m] = *(const s16x8*)(qs + row * 128 + (((ksi * 4 + lg) ^ (lr & 7)) << 4));
        }
#pragma unroll
        for (int j = 0; j < 4; j++) {
            const int vr = j * 16 + lr;
            bF[ksi][j] = *(const s16x8*)(ks + vr * 128 + (((ksi * 4 + lg) ^ (lr & 7)) << 4));
        }
    }
#pragma unroll
    for (int ksi = 0; ksi < 2; ksi++)
#pragma unroll
        for (int m = 0; m < 4; m++)
#pragma unroll
            for (int j = 0; j < 4; j++)
                acc[m][j] = __builtin_amdgcn_mfma_f32_16x16x32_bf16(aF[ksi][m], bF[ksi][j], acc[m][j], 0, 0, 0);

#pragma unroll
    for (int m = 0; m < 4; m++) {
#pragma unroll
        for (int j = 0; j < 4; j++) {
#pragma unroll
            for (int r = 0; r < 4; r++) {
                const int lrow = w * 64 + m * 16 + lg * 4 + r;
                const int col = j * 16 + lr;
                const size_t idx = ((size_t)(b * 1024 + n0 + lrow)) * 512 + hh * 64 + col;
                const short qv = *(const short*)(qs + lrow * 128 + ((((col >> 3) ^ (lrow & 7)) << 4)) + (col & 7) * 2);
                xs[idx] = xs[idx] + acc[m][j][r] + b2f(qv) * __bfloat162float(vc[idx]);
            }
        }
    }
}

// ---------------- workspace layout (bytes), full-batch ----------------------
// ktvp/csp live in the cur region (dead between qkv GEMM and LN2).
static constexpr size_t OFF_WQ   = 0;
static constexpr size_t OFF_W1   = 1572864;
static constexpr size_t OFF_W2   = 3670016;
static constexpr size_t OFF_CUR  = 5767168;
static constexpr size_t OFF_H2B  = 5767168;     // over cur: write only after last cur read
static constexpr size_t OFF_KTVP = 5767168;     // over cur: live only between qkv and LN2
static constexpr size_t OFF_CSP  = 14155776;
static constexpr size_t OFF_QKV  = 72876032;
static constexpr size_t OFF_HG   = 72876032;
static constexpr size_t OFF_VC   = 173539328;
static constexpr size_t OFF_H2A  = 139984896;
static constexpr size_t WS_NEED  = 207618048;   // ~198MB (ws >= 215.5MB confirmed)

extern "C" void kernel_launch(void* const* d_in, const int* in_sizes, int n_in,
                              void* d_out, int out_size, void* d_ws, size_t ws_size,
                              hipStream_t stream)
{
    const float* x     = (const float*)d_in[0];
    const float* cpe_w = (const float*)d_in[1];
    const float* cpe_b = (const float*)d_in[2];
    const float* ln1_w = (const float*)d_in[3];
    const float* ln1_b = (const float*)d_in[4];
    const float* qkv_w = (const float*)d_in[5];
    const float* crpe_w= (const float*)d_in[6];
    const float* crpe_b= (const float*)d_in[7];
    const float* ln2_w = (const float*)d_in[8];
    const float* ln2_b = (const float*)d_in[9];
    const float* fc1_w = (const float*)d_in[10];
    const float* fc1_b = (const float*)d_in[11];
    const float* dw_w  = (const float*)d_in[12];
    const float* dw_b  = (const float*)d_in[13];
    const float* fc2_w = (const float*)d_in[14];
    const float* fc2_b = (const float*)d_in[15];
    float* spine = (float*)d_out;
    char* ws = (char*)d_ws;

    if (ws_size < WS_NEED) {
        diag_k<<<1, 1, 0, stream>>>(spine, (float)ws_size);
        return;
    }

    bf16*  wq   = (bf16*)(ws + OFF_WQ);
    bf16*  w1   = (bf16*)(ws + OFF_W1);
    bf16*  w2b  = (bf16*)(ws + OFF_W2);
    bf16*  cur  = (bf16*)(ws + OFF_CUR);
    bf16*  qkv  = (bf16*)(ws + OFF_QKV);
    bf16*  vc   = (bf16*)(ws + OFF_VC);
    float* ktvp = (float*)(ws + OFF_KTVP);
    float* csp  = (float*)(ws + OFF_CSP);
    bf16*  hg   = (bf16*)(ws + OFF_HG);
    bf16*  h2a  = (bf16*)(ws + OFF_H2A);
    bf16*  h2b  = (bf16*)(ws + OFF_H2B);

    // weights -> bf16 (w2 native [512][2048])
    f2bf_k<<<(1536 * 512 / 8 + 255) / 256, 256, 0, stream>>>(qkv_w, wq, 1536 * 512);
    f2bf_k<<<(2048 * 512 / 8 + 255) / 256, 256, 0, stream>>>(fc1_w, w1, 2048 * 512);
    f2bf_k<<<(2048 * 512 / 8 + 255) / 256, 256, 0, stream>>>(fc2_w, w2b, 512 * 2048);

    // CPE (fp32, 64-ch groups): spine = x + dwconv(x) + cpe_b
    conv4_k<float, float, true, 1><<<32 * 8 * 4, 256, 0, stream>>>(x, 512, 0, cpe_w, cpe_b, spine, 512, 3);

    const int M = 32768;
    // LN1
    ln_k<<<M / 4, 256, 0, stream>>>(spine, ln1_w, ln1_b, cur);
    // qkv: 768 blocks (XCD-swizzled 256^2 8-phase)
    gemm8p_k<0, 512, 6><<<768, 512, 0, stream>>>(cur, wq, nullptr, qkv, M, 1536);
    // ktv: token-split partials (cur region now dead)
    ktv3_k<<<512, 256, 0, stream>>>(qkv, ktvp, csp);
    // crpe conv on v
    conv4_k<bf16, bf16, false, 2><<<32 * 4 * 4, 256, 0, stream>>>(qkv, 1536, 1024, crpe_w, crpe_b, vc, 512, 2);
    // attention output (fused reduce + MFMA), in place on spine
    attnout3_k<<<32 * 8 * 4, 256, 0, stream>>>(spine, qkv, ktvp, csp, vc);
    // LN2 (rewrites cur; ktvp/csp dead)
    ln_k<<<M / 4, 256, 0, stream>>>(spine, ln2_w, ln2_b, cur);

    // MLP (lifetime-correct order): h0 -> h2a first; h2b (over cur) LAST
    gemm8ps_k<1, 512, 8, false><<<2048, 512, 0, stream>>>(cur, nullptr, w1, fc1_b, nullptr, hg, nullptr, M, 1024);
    conv4_k<bf16, bf16, true, 2><<<32 * 8 * 4, 256, 0, stream>>>(hg, 1024, 0, dw_w, dw_b, h2a, 1024, 3);
    gemm8ps_k<1, 512, 8, false><<<2048, 512, 0, stream>>>(cur, nullptr, w1 + (size_t)1024 * 512, fc1_b + 1024, nullptr, hg, nullptr, M, 1024);
    conv4_k<bf16, bf16, true, 2><<<32 * 8 * 4, 256, 0, stream>>>(hg, 1024, 0, dw_w + (size_t)1024 * 9, dw_b + 1024, h2b, 1024, 3);
    // fc2: K=2048 dual-A, BM=BN=128, 1024 blocks (2/CU), counted-vmcnt 8-phase
    gemm8ps_k<2, 2048, 4, true><<<1024, 512, 0, stream>>>(h2a, h2b, w2b, fc2_b, spine, nullptr, spine, M, 512);
}

// Round 21
// 463.883 us; speedup vs baseline: 1.1324x; 1.0037x over previous
//
#include <hip/hip_runtime.h>
#include <hip/hip_bf16.h>

using bf16 = __hip_bfloat16;
using s16x4 = __attribute__((ext_vector_type(4))) short;
using s16x8 = __attribute__((ext_vector_type(8))) short;
using f32x4 = __attribute__((ext_vector_type(4))) float;

#define DI __device__ __forceinline__

template <int N> DI void wvm() {
    if constexpr (N == 8) asm volatile("s_waitcnt vmcnt(8)" ::: "memory");
    else if constexpr (N == 4) asm volatile("s_waitcnt vmcnt(4)" ::: "memory");
    else if constexpr (N == 2) asm volatile("s_waitcnt vmcnt(2)" ::: "memory");
    else if constexpr (N == 1) asm volatile("s_waitcnt vmcnt(1)" ::: "memory");
    else asm volatile("s_waitcnt vmcnt(0)" ::: "memory");
}

DI float b2f(short s) { union { unsigned u; float f; } z; z.u = ((unsigned)(unsigned short)s) << 16; return z.f; }
DI short f2b(float f) { bf16 t = __float2bfloat16(f); return *(short*)&t; }

// fast gelu: tanh form, |err| ~1e-3 absolute, far under threshold
DI float gelu_f(float x) {
    const float t = 0.7978845608f * x * (1.f + 0.044715f * x * x);
    const float e = __expf(2.f * t);
    const float th = 1.f - 2.f / (e + 1.f);
    return 0.5f * x * (1.f + th);
}

DI void ld8(const bf16* p, float* f) {
    s16x8 x = *(const s16x8*)(const void*)p;
#pragma unroll
    for (int c = 0; c < 8; c++) f[c] = b2f(x[c]);
}
DI void ld8(const float* p, float* f) {
    float4 a = *(const float4*)p, b = *(const float4*)(p + 4);
    f[0]=a.x; f[1]=a.y; f[2]=a.z; f[3]=a.w; f[4]=b.x; f[5]=b.y; f[6]=b.z; f[7]=b.w;
}

typedef const __attribute__((address_space(1))) void* gp_t;
typedef __attribute__((address_space(3))) void* lp_t;
DI void gload_lds16(const void* g, void* l) {
    __builtin_amdgcn_global_load_lds((gp_t)g, (lp_t)l, 16, 0, 0);
}

// ---------------- diagnostic ----------------
__global__ void diag_k(float* out, float v) { out[0] = v; }

// ---------------- fp32 -> bf16 weight conversion (8/thread) ----------------
__global__ void f2bf_k(const float* __restrict__ in, bf16* __restrict__ out, int n) {
    int i = (blockIdx.x * 256 + threadIdx.x) * 8;
    if (i >= n) return;
    float f[8];
    ld8(in + i, f);
    s16x8 o;
#pragma unroll
    for (int c = 0; c < 8; c++) o[c] = f2b(f[c]);
    *(s16x8*)(void*)(out + i) = o;
}

// ---------------- depthwise 3x3 conv v4 ----------------
DI void tap10(const float* r, float w0, float w1, float w2, float* acc) {
#pragma unroll
    for (int i = 0; i < 8; i++)
        acc[i] += w0 * r[i] + w1 * r[i + 1] + w2 * r[i + 2];
}

template <typename TI, typename TO, bool RESID, int CPL>
__global__ __launch_bounds__(256) void conv4_k(
    const TI* in, long rs, long coff,
    const float* __restrict__ w, const float* __restrict__ bias,
    TO* out, long ors, int gshift)
{
    constexpr int CH = 64 * CPL;
    constexpr int ECNT = CH / 8;
    __shared__ float buf[2][CH][33];
    const int t = threadIdx.x;
    const int band = blockIdx.x & 3;
    const int cg = (blockIdx.x >> 2) & ((1 << gshift) - 1);
    const int img = blockIdx.x >> (2 + gshift);
    const int y0 = band * 8;

    const int spx = t >> 3;
    const int sce = (t & 7) * ECNT;
    const TI* gsrc = in + ((long)img << 10) * rs + coff + (long)cg * CH + sce;

    const int c = t & 63;
    const int xb = (t >> 6) * 8;

    float wv9[9][CPL], bw[CPL];
#pragma unroll
    for (int p = 0; p < CPL; p++) {
        const int gch = cg * CH + c * CPL + p;
#pragma unroll
        for (int j = 0; j < 9; j++) wv9[j][p] = w[gch * 9 + j];
        bw[p] = bias[gch];
    }

    auto stage = [&](int row) {
        float f[ECNT];
        ld8(gsrc + (long)(row * 32 + spx) * rs, f);
        if constexpr (ECNT == 16) ld8(gsrc + (long)(row * 32 + spx) * rs + 8, f + 8);
        float* d = &buf[row & 1][0][0];
#pragma unroll
        for (int k = 0; k < ECNT; k++) {
            const int ch = sce + k;
            const int rr = (CPL == 2) ? ((ch & 1) * 64 + (ch >> 1)) : ch;
            d[rr * 33 + spx] = f[k];
        }
    };
    auto slice = [&](int row, float r[CPL][10]) {
#pragma unroll
        for (int p = 0; p < CPL; p++) {
            const float* s = &buf[row & 1][c + p * 64][0];
            r[p][0] = (xb == 0) ? 0.f : s[xb - 1];
#pragma unroll
            for (int i = 0; i < 8; i++) r[p][1 + i] = s[xb + i];
            r[p][9] = (xb + 8 >= 32) ? 0.f : s[xb + 8];
        }
    };
    auto zero = [&](float r[CPL][10]) {
#pragma unroll
        for (int p = 0; p < CPL; p++)
#pragma unroll
            for (int i = 0; i < 10; i++) r[p][i] = 0.f;
    };

    float r0[CPL][10], r1[CPL][10], r2[CPL][10];
    if (y0 > 0) stage(y0 - 1);
    __syncthreads();
    if (y0 > 0) slice(y0 - 1, r0); else zero(r0);
    stage(y0);
    __syncthreads();
    slice(y0, r1);

    for (int y = y0; y < y0 + 8; ++y) {
        const int yn = y + 1;
        if (yn <= 31) stage(yn);
        __syncthreads();
        if (yn <= 31) slice(yn, r2); else zero(r2);
        float acc[CPL][8];
#pragma unroll
        for (int p = 0; p < CPL; p++) {
#pragma unroll
            for (int i = 0; i < 8; i++) acc[p][i] = bw[p];
            tap10(r0[p], wv9[0][p], wv9[1][p], wv9[2][p], acc[p]);
            tap10(r1[p], wv9[3][p], wv9[4][p], wv9[5][p], acc[p]);
            tap10(r2[p], wv9[6][p], wv9[7][p], wv9[8][p], acc[p]);
            if (RESID) {
#pragma unroll
                for (int i = 0; i < 8; i++) acc[p][i] += r1[p][i + 1];
            }
        }
        TO* o = out + ((long)(img * 1024 + y * 32 + xb)) * ors + (long)cg * CH + c * CPL;
#pragma unroll
        for (int i = 0; i < 8; i++) {
            if constexpr (CPL == 2 && sizeof(TO) == 2) {
                const unsigned u = (unsigned)(unsigned short)f2b(acc[0][i]) |
                                   ((unsigned)(unsigned short)f2b(acc[1][i]) << 16);
                *(unsigned*)(void*)(o + (long)i * ors) = u;
            } else {
                o[(long)i * ors] = (TO)acc[0][i];
            }
        }
#pragma unroll
        for (int p = 0; p < CPL; p++)
#pragma unroll
            for (int i = 0; i < 10; i++) { r0[p][i] = r1[p][i]; r1[p][i] = r2[p][i]; }
    }
}

// ---------------- LayerNorm over C=512, fp32 in -> bf16 out ----------------
__global__ __launch_bounds__(256) void ln_k(const float* __restrict__ x,
                                            const float* __restrict__ w,
                                            const float* __restrict__ bp,
                                            bf16* __restrict__ out)
{
    const size_t row = blockIdx.x * 4 + (threadIdx.x >> 6);
    const int t = threadIdx.x & 63;
    const float* xr = x + row * 512;
    alignas(16) float v[8];
    *(float4*)&v[0] = *(const float4*)(xr + t * 8);
    *(float4*)&v[4] = *(const float4*)(xr + t * 8 + 4);
    float s = 0.f;
#pragma unroll
    for (int j = 0; j < 8; j++) s += v[j];
#pragma unroll
    for (int mm = 32; mm; mm >>= 1) s += __shfl_xor(s, mm);
    const float mu = s * (1.f / 512.f);
    float q = 0.f;
#pragma unroll
    for (int j = 0; j < 8; j++) { v[j] -= mu; q += v[j] * v[j]; }
#pragma unroll
    for (int mm = 32; mm; mm >>= 1) q += __shfl_xor(q, mm);
    const float rstd = rsqrtf(q * (1.f / 512.f) + 1e-6f);
    alignas(16) float wv[8], bv[8];
    *(float4*)&wv[0] = *(const float4*)(w + t * 8);
    *(float4*)&wv[4] = *(const float4*)(w + t * 8 + 4);
    *(float4*)&bv[0] = *(const float4*)(bp + t * 8);
    *(float4*)&bv[4] = *(const float4*)(bp + t * 8 + 4);
    alignas(16) bf16 o[8];
#pragma unroll
    for (int j = 0; j < 8; j++) o[j] = __float2bfloat16(v[j] * rstd * wv[j] + bv[j]);
    *(uint4*)(out + row * 512 + t * 8) = *(const uint4*)o;
}

// ---------------- 8-phase 256x256 bf16 MFMA GEMM (qkv, fc1) -----------------
template <int EPI, int K, int NY>
__global__ __launch_bounds__(512) void gemm8p_k(
    const bf16* __restrict__ A, const bf16* __restrict__ Bw,
    const float* __restrict__ bias, bf16* __restrict__ outb, int M, int Nn)
{
    constexpr int KT = K / 64;
    __shared__ __align__(16) char lds[131072];
    char* ldsA = lds;
    char* ldsB = lds + 65536;
    const int t = threadIdx.x;
    const int lane = t & 63;
    const int w = t >> 6;
    const int wr = w >> 2, wc = w & 3;
    const int nwg = 128 * NY;
    const int swz = (blockIdx.x & 7) * (nwg >> 3) + (blockIdx.x >> 3);
    const int m0 = (swz / NY) * 256;
    const int n0 = (swz % NY) * 256;
    const int lr = lane & 15, lg = lane >> 4;

    f32x4 acc[8][4] = {};

    const int srow = lane >> 3;
    const int ssrc = 8 * ((lane & 7) ^ srow);

    auto SA = [&](int b, int kt, int h) {
#pragma unroll
        for (int j = 0; j < 2; j++) {
            const int lrow0 = j * 64 + w * 8;
            const int R0 = j * 128 + h * 64 + (lrow0 & 63);
            gload_lds16(A + (size_t)(m0 + R0 + srow) * K + kt * 64 + ssrc,
                        ldsA + ((b * 2 + h) * 128 + lrow0) * 128);
        }
    };
    auto SB = [&](int b, int kt, int h) {
#pragma unroll
        for (int j = 0; j < 2; j++) {
            const int lrow0 = j * 64 + w * 8;
            const int R0 = (lrow0 >> 5) * 64 + h * 32 + (lrow0 & 31);
            gload_lds16(Bw + (size_t)(n0 + R0 + srow) * K + kt * 64 + ssrc,
                        ldsB + ((b * 2 + h) * 128 + lrow0) * 128);
        }
    };
    auto RA = [&](int b, int h, int m, int ks) -> s16x8 {
        return *(const s16x8*)(ldsA + ((b * 2 + h) * 128 + wr * 64 + m * 16 + lr) * 128
                               + (((ks * 4 + lg) ^ (lr & 7)) << 4));
    };
    auto RB = [&](int b, int h, int n, int ks) -> s16x8 {
        return *(const s16x8*)(ldsB + ((b * 2 + h) * 128 + wc * 32 + n * 16 + lr) * 128
                               + (((ks * 4 + lg) ^ (lr & 7)) << 4));
    };
    auto MM = [&](int mb, int nb, s16x8 (&a)[2][4], s16x8 (&b)[2][2]) {
#pragma unroll
        for (int ks = 0; ks < 2; ks++)
#pragma unroll
            for (int m = 0; m < 4; m++)
#pragma unroll
                for (int n = 0; n < 2; n++)
                    acc[mb + m][nb + n] =
                        __builtin_amdgcn_mfma_f32_16x16x32_bf16(a[ks][m], b[ks][n], acc[mb + m][nb + n], 0, 0, 0);
    };

    SA(0, 0, 0); SB(0, 0, 0); SA(0, 0, 1); SB(0, 0, 1);
    SA(1, 1, 0); SB(1, 1, 0);
    wvm<8>();
    __builtin_amdgcn_s_barrier();

    s16x8 aLo[2][4], aHi[2][4], bLo[2][2], bHi[2][2];
    auto TILE = [&](int kt) {
        const int b = kt & 1;
#pragma unroll
        for (int ks = 0; ks < 2; ks++) {
#pragma unroll
            for (int m = 0; m < 4; m++) aLo[ks][m] = RA(b, 0, m, ks);
#pragma unroll
            for (int n = 0; n < 2; n++) bLo[ks][n] = RB(b, 0, n, ks);
        }
        if (kt + 1 < KT) SA(b ^ 1, kt + 1, 1);
        __builtin_amdgcn_s_barrier();
        __builtin_amdgcn_s_setprio(1);
        MM(0, 0, aLo, bLo);
        __builtin_amdgcn_s_setprio(0);
        if (kt + 1 < KT) wvm<8>(); else wvm<2>();
        __builtin_amdgcn_s_barrier();
#pragma unroll
        for (int ks = 0; ks < 2; ks++)
#pragma unroll
            for (int m = 0; m < 4; m++) aHi[ks][m] = RA(b, 1, m, ks);
        if (kt + 1 < KT) SB(b ^ 1, kt + 1, 1);
        __builtin_amdgcn_s_barrier();
        __builtin_amdgcn_s_setprio(1);
        MM(4, 0, aHi, bLo);
        __builtin_amdgcn_s_setprio(0);
        if (kt + 1 < KT) wvm<8>(); else wvm<0>();
        __builtin_amdgcn_s_barrier();
#pragma unroll
        for (int ks = 0; ks < 2; ks++)
#pragma unroll
            for (int n = 0; n < 2; n++) bHi[ks][n] = RB(b, 1, n, ks);
        if (kt + 2 < KT) SA(b, kt + 2, 0);
        __builtin_amdgcn_s_barrier();
        __builtin_amdgcn_s_setprio(1);
        MM(4, 2, aHi, bHi);
        __builtin_amdgcn_s_setprio(0);
        __builtin_amdgcn_s_barrier();
        if (kt + 2 < KT) SB(b, kt + 2, 0);
        __builtin_amdgcn_s_barrier();
        __builtin_amdgcn_s_setprio(1);
        MM(0, 2, aLo, bHi);
        __builtin_amdgcn_s_setprio(0);
        if (kt + 2 < KT) { wvm<8>(); __builtin_amdgcn_s_barrier(); }
        else if (kt + 1 < KT) { wvm<4>(); __builtin_amdgcn_s_barrier(); }
    };

#pragma unroll
    for (int kt = 0; kt < KT; ++kt) TILE(kt);

#pragma unroll
    for (int i = 0; i < 8; i++) {
#pragma unroll
        for (int j = 0; j < 4; j++) {
            const int col = n0 + wc * 64 + j * 16 + lr;
            float bcol = 0.f;
            if constexpr (EPI >= 1) bcol = bias[col];
#pragma unroll
            for (int r = 0; r < 4; r++) {
                const int row = m0 + wr * 128 + i * 16 + lg * 4 + r;
                float v = acc[i][j][r] + bcol;
                const size_t idx = (size_t)row * Nn + col;
                outb[idx] = __float2bfloat16(EPI == 1 ? gelu_f(v) : v);
            }
        }
    }
}

// ---------------- small-tile 8-phase GEMM: BM=BN=128, 64KB LDS, 2/CU --------
// Counted-vmcnt schedule (steady 4, tails 1/0/2). DUAL: A=K-half0, A2=K-half1.
// EPI 2: +bias +resid fp32 (in-place ok).
template <int EPI, int K, int NY, bool DUAL>
__global__ __launch_bounds__(512) void gemm8ps_k(
    const bf16* __restrict__ A, const bf16* __restrict__ A2,
    const bf16* __restrict__ Bw, const float* __restrict__ bias,
    const float* resid, bf16* __restrict__ outb, float* outf, int M, int Nn)
{
    constexpr int KT = K / 64;
    constexpr int LDA = DUAL ? K / 2 : K;
    __shared__ __align__(16) char lds[65536];
    char* ldsA = lds;
    char* ldsB = lds + 32768;
    const int t = threadIdx.x;
    const int lane = t & 63;
    const int w = t >> 6;
    const int wr = w >> 2, wc = w & 3;
    const int nwg = gridDim.x;
    const int swz = (blockIdx.x & 7) * (nwg >> 3) + (blockIdx.x >> 3);
    const int m0 = (swz / NY) * 128;
    const int n0 = (swz % NY) * 128;
    const int lr = lane & 15, lg = lane >> 4;

    f32x4 acc[4][2] = {};

    const int srow = lane >> 3;
    const int ssrc = 8 * ((lane & 7) ^ srow);
    const int lrow0 = w * 8;

    auto SA = [&](int b, int kt, int h) {
        const bf16* Ab = A;
        int ktl = kt;
        if constexpr (DUAL) { if (kt >= KT / 2) { Ab = A2; ktl = kt - KT / 2; } }
        const int R0 = h * 64 + lrow0;
        gload_lds16(Ab + (size_t)(m0 + R0 + srow) * LDA + ktl * 64 + ssrc,
                    ldsA + ((b * 2 + h) * 64 + lrow0) * 128);
    };
    auto SB = [&](int b, int kt, int h) {
        const int R0 = (lrow0 >> 4) * 32 + h * 16 + (lrow0 & 15);
        gload_lds16(Bw + (size_t)(n0 + R0 + srow) * K + kt * 64 + ssrc,
                    ldsB + ((b * 2 + h) * 64 + lrow0) * 128);
    };
    auto RA = [&](int b, int h, int m, int ks) -> s16x8 {
        return *(const s16x8*)(ldsA + ((b * 2 + h) * 64 + wr * 32 + m * 16 + lr) * 128
                               + (((ks * 4 + lg) ^ (lr & 7)) << 4));
    };
    auto RB = [&](int b, int h, int ks) -> s16x8 {
        return *(const s16x8*)(ldsB + ((b * 2 + h) * 64 + wc * 16 + lr) * 128
                               + (((ks * 4 + lg) ^ (lr & 7)) << 4));
    };
    auto MM = [&](int hm, int hn, s16x8 (&a)[2][2], s16x8 (&bb)[2]) {
#pragma unroll
        for (int ks = 0; ks < 2; ks++)
#pragma unroll
            for (int m = 0; m < 2; m++)
                acc[hm * 2 + m][hn] =
                    __builtin_amdgcn_mfma_f32_16x16x32_bf16(a[ks][m], bb[ks], acc[hm * 2 + m][hn], 0, 0, 0);
    };

    SA(0, 0, 0); SB(0, 0, 0); SA(0, 0, 1); SB(0, 0, 1);
    SA(1, 1, 0); SB(1, 1, 0);
    wvm<4>();
    __builtin_amdgcn_s_barrier();

    s16x8 aLo[2][2], aHi[2][2], bLo[2], bHi[2];
#pragma unroll 2
    for (int kt = 0; kt < KT; ++kt) {
        const int b = kt & 1;
        // phase 0: (M-lo x N-lo); stage A-hi(kt+1)
#pragma unroll
        for (int ks = 0; ks < 2; ks++) {
#pragma unroll
            for (int m = 0; m < 2; m++) aLo[ks][m] = RA(b, 0, m, ks);
            bLo[ks] = RB(b, 0, ks);
        }
        if (kt + 1 < KT) SA(b ^ 1, kt + 1, 1);
        __builtin_amdgcn_s_barrier();
        __builtin_amdgcn_s_setprio(1);
        MM(0, 0, aLo, bLo);
        __builtin_amdgcn_s_setprio(0);
        if (kt + 1 < KT) wvm<4>(); else wvm<1>();
        __builtin_amdgcn_s_barrier();
        // phase 1: (M-hi x N-lo); stage B-hi(kt+1)
#pragma unroll
        for (int ks = 0; ks < 2; ks++)
#pragma unroll
            for (int m = 0; m < 2; m++) aHi[ks][m] = RA(b, 1, m, ks);
        if (kt + 1 < KT) SB(b ^ 1, kt + 1, 1);
        __builtin_amdgcn_s_barrier();
        __builtin_amdgcn_s_setprio(1);
        MM(1, 0, aHi, bLo);
        __builtin_amdgcn_s_setprio(0);
        if (kt + 1 < KT) wvm<4>(); else wvm<0>();
        __builtin_amdgcn_s_barrier();
        // phase 2: (M-hi x N-hi); stage A-lo(kt+2)
#pragma unroll
        for (int ks = 0; ks < 2; ks++) bHi[ks] = RB(b, 1, ks);
        if (kt + 2 < KT) SA(b, kt + 2, 0);
        __builtin_amdgcn_s_barrier();
        __builtin_amdgcn_s_setprio(1);
        MM(1, 1, aHi, bHi);
        __builtin_amdgcn_s_setprio(0);
        __builtin_amdgcn_s_barrier();
        // phase 3: (M-lo x N-hi); stage B-lo(kt+2)
        if (kt + 2 < KT) SB(b, kt + 2, 0);
        __builtin_amdgcn_s_barrier();
        __builtin_amdgcn_s_setprio(1);
        MM(0, 1, aLo, bHi);
        __builtin_amdgcn_s_setprio(0);
        if (kt + 2 < KT) { wvm<4>(); __builtin_amdgcn_s_barrier(); }
        else if (kt + 1 < KT) { wvm<2>(); __builtin_amdgcn_s_barrier(); }
    }

#pragma unroll
    for (int mf = 0; mf < 4; mf++) {
#pragma unroll
        for (int nf = 0; nf < 2; nf++) {
            const int col = n0 + wc * 32 + nf * 16 + lr;
            float bcol = 0.f;
            if constexpr (EPI >= 1) bcol = bias[col];
#pragma unroll
            for (int r = 0; r < 4; r++) {
                const int row = m0 + (mf >> 1) * 64 + wr * 32 + (mf & 1) * 16 + lg * 4 + r;
                float v = acc[mf][nf][r] + bcol;
                const size_t idx = (size_t)row * Nn + col;
                if (EPI == 2) outf[idx] = v + resid[idx];
                else outb[idx] = __float2bfloat16(EPI == 1 ? gelu_f(v) : v);
            }
        }
    }
}

// ---------------- ktv v3: token-split MFMA partials (512 blocks, 2/CU) ------
__global__ __launch_bounds__(256) void ktv3_k(const bf16* __restrict__ qkv,
                                              float* __restrict__ ktvp,
                                              float* __restrict__ csp)
{
    __shared__ __align__(16) char P[64 * 128];
    __shared__ __align__(16) char Vt[64 * 128];
    __shared__ float csl[64 * 5];
    const int t = threadIdx.x;
    const int bh = blockIdx.x >> 1, half = blockIdx.x & 1;
    const int b = bh >> 3, hh = bh & 7;
    const int lane = t & 63, w = t >> 6;
    const int lr = lane & 15, lg = lane >> 4;

    const int n_r = t >> 2;
    const int k0 = (t & 3) * 16;
    const bf16* kbase = qkv + (size_t)(b * 1024) * 1536 + 512 + hh * 64 + k0;
    const bf16* vbase = kbase + 512;

    const int kq = t & 63, qq = t >> 6;
    float cacc = 0.f;

    f32x4 acc[4] = {};

    for (int n0 = half * 512; n0 < half * 512 + 512; n0 += 64) {
        const uint4 ka = *(const uint4*)(kbase + (size_t)(n0 + n_r) * 1536);
        const uint4 kb2 = *(const uint4*)(kbase + (size_t)(n0 + n_r) * 1536 + 8);
        const uint4 va = *(const uint4*)(vbase + (size_t)(n0 + n_r) * 1536);
        const uint4 vb2 = *(const uint4*)(vbase + (size_t)(n0 + n_r) * 1536 + 8);
        __syncthreads();
        {
            const short* ke = (const short*)&ka;
            const short* ke2 = (const short*)&kb2;
            const short* ve = (const short*)&va;
            const short* ve2 = (const short*)&vb2;
            const int nslot = ((n_r >> 3) << 4);
            const int nbyte = (n_r & 7) * 2;
#pragma unroll
            for (int j = 0; j < 16; j++) {
                const int row = k0 + j;
                const short kv = j < 8 ? ke[j] : ke2[j - 8];
                const short vv = j < 8 ? ve[j] : ve2[j - 8];
                const int off = row * 128 + (nslot ^ ((row & 7) << 4)) + nbyte;
                *(short*)(P + off) = f2b(__expf(b2f(kv)));
                *(short*)(Vt + off) = vv;
            }
        }
        __syncthreads();
        {
            const char* pr = P + kq * 128;
            const int sw = (kq & 7) << 4;
            s16x8 x0 = *(const s16x8*)(pr + (((qq * 2) << 4) ^ sw));
            s16x8 x1 = *(const s16x8*)(pr + (((qq * 2 + 1) << 4) ^ sw));
#pragma unroll
            for (int j = 0; j < 8; j++) cacc += b2f(x0[j]) + b2f(x1[j]);
        }
#pragma unroll
        for (int ks2 = 0; ks2 < 2; ks2++) {
            s16x8 aF = *(const s16x8*)(Vt + (w * 16 + lr) * 128 + (((ks2 * 4 + lg) ^ (lr & 7)) << 4));
            s16x8 bF[4];
#pragma unroll
            for (int j = 0; j < 4; j++)
                bF[j] = *(const s16x8*)(P + (j * 16 + lr) * 128 + (((ks2 * 4 + lg) ^ (lr & 7)) << 4));
#pragma unroll
            for (int j = 0; j < 4; j++)
                acc[j] = __builtin_amdgcn_mfma_f32_16x16x32_bf16(aF, bF[j], acc[j], 0, 0, 0);
        }
    }
    __syncthreads();
    csl[kq * 5 + qq] = cacc;
    __syncthreads();
    if (t < 64) csp[blockIdx.x * 64 + t] = csl[t * 5] + csl[t * 5 + 1] + csl[t * 5 + 2] + csl[t * 5 + 3];

    float* o = ktvp + (size_t)blockIdx.x * 4096;
#pragma unroll
    for (int j = 0; j < 4; j++) {
        const int col = j * 16 + lr;
#pragma unroll
        for (int r = 0; r < 4; r++) {
            const int vrow = w * 16 + lg * 4 + r;
            o[vrow * 64 + col] = acc[j][r];
        }
    }
}

// ---------------- attnout v3: fused ktv-reduce + MFMA q@ktvT + crpe + resid --
__global__ __launch_bounds__(256) void attnout3_k(
    float* xs, const bf16* __restrict__ qkv,
    const float* __restrict__ ktvp, const float* __restrict__ csp,
    const bf16* __restrict__ vc)
{
    __shared__ __align__(16) char qs[256 * 128];
    __shared__ __align__(16) char ks[64 * 128];
    const int t = threadIdx.x;
    const int bid = blockIdx.x;
    const int b = bid >> 5, hh = (bid >> 2) & 7, nc = bid & 3;
    const int bh = b * 8 + hh;
    const int n0 = nc * 256;
    const int lane = t & 63, w = t >> 6;
    const int lr = lane & 15, lg = lane >> 4;

    {
        const int r0 = t >> 3, sl = t & 7;
#pragma unroll
        for (int it = 0; it < 8; it++) {
            const int row = it * 32 + r0;
            const uint4 v = *(const uint4*)(qkv + ((size_t)(b * 1024 + n0 + row)) * 1536 + hh * 64 + sl * 8);
            *(uint4*)(qs + row * 128 + ((sl ^ (row & 7)) << 4)) = v;
        }
        // fused reduce: ktvT[vr][col] = (p0+p1) * 0.125/(cs0+cs1), bf16, swizzled
#pragma unroll
        for (int it = 0; it < 2; it++) {
            const int u = it * 256 + t;
            const int vr = u >> 3, sl2 = u & 7;
            const float* p0 = ktvp + (size_t)(bh * 2) * 4096 + vr * 64 + sl2 * 8;
            const float* p1 = p0 + 4096;
            s16x8 o;
#pragma unroll
            for (int j = 0; j < 8; j++) {
                const int col = sl2 * 8 + j;
                const float cs = csp[(bh * 2) * 64 + col] + csp[(bh * 2 + 1) * 64 + col];
                o[j] = f2b((p0[j] + p1[j]) * (0.125f / cs));
            }
            *(s16x8*)(void*)(ks + vr * 128 + ((sl2 ^ (vr & 7)) << 4)) = o;
        }
    }
    __syncthreads();

    f32x4 acc[4][4] = {};
    s16x8 aF[2][4], bF[2][4];
#pragma unroll
    for (int ksi = 0; ksi < 2; ksi++) {
#pragma unroll
        for (int m = 0; m < 4; m++) {
            const int row = w * 64 + m * 16 + lr;
            aF[ksi][m] = *(const s16x8*)(qs + row * 128 + (((ksi * 4 + lg) ^ (lr & 7)) << 4));
        }
#pragma unroll
        for (int j = 0; j < 4; j++) {
            const int vr = j * 16 + lr;
            bF[ksi][j] = *(const s16x8*)(ks + vr * 128 + (((ksi * 4 + lg) ^ (lr & 7)) << 4));
        }
    }
#pragma unroll
    for (int ksi = 0; ksi < 2; ksi++)
#pragma unroll
        for (int m = 0; m < 4; m++)
#pragma unroll
            for (int j = 0; j < 4; j++)
                acc[m][j] = __builtin_amdgcn_mfma_f32_16x16x32_bf16(aF[ksi][m], bF[ksi][j], acc[m][j], 0, 0, 0);

#pragma unroll
    for (int m = 0; m < 4; m++) {
#pragma unroll
        for (int j = 0; j < 4; j++) {
#pragma unroll
            for (int r = 0; r < 4; r++) {
                const int lrow = w * 64 + m * 16 + lg * 4 + r;
                const int col = j * 16 + lr;
                const size_t idx = ((size_t)(b * 1024 + n0 + lrow)) * 512 + hh * 64 + col;
                const short qv = *(const short*)(qs + lrow * 128 + ((((col >> 3) ^ (lrow & 7)) << 4)) + (col & 7) * 2);
                xs[idx] = xs[idx] + acc[m][j][r] + b2f(qv) * __bfloat162float(vc[idx]);
            }
        }
    }
}

// ---------------- workspace layout (bytes), full-batch ----------------------
// ktvp/csp live in the cur region (dead between qkv GEMM and LN2).
static constexpr size_t OFF_WQ   = 0;
static constexpr size_t OFF_W1   = 1572864;
static constexpr size_t OFF_W2   = 3670016;
static constexpr size_t OFF_CUR  = 5767168;
static constexpr size_t OFF_H2B  = 5767168;     // over cur: write only after last cur read
static constexpr size_t OFF_KTVP = 5767168;     // over cur: live only between qkv and LN2
static constexpr size_t OFF_CSP  = 14155776;
static constexpr size_t OFF_QKV  = 72876032;
static constexpr size_t OFF_HG   = 72876032;
static constexpr size_t OFF_VC   = 173539328;
static constexpr size_t OFF_H2A  = 139984896;
static constexpr size_t WS_NEED  = 207618048;   // ~198MB (ws >= 215.5MB confirmed)

extern "C" void kernel_launch(void* const* d_in, const int* in_sizes, int n_in,
                              void* d_out, int out_size, void* d_ws, size_t ws_size,
                              hipStream_t stream)
{
    const float* x     = (const float*)d_in[0];
    const float* cpe_w = (const float*)d_in[1];
    const float* cpe_b = (const float*)d_in[2];
    const float* ln1_w = (const float*)d_in[3];
    const float* ln1_b = (const float*)d_in[4];
    const float* qkv_w = (const float*)d_in[5];
    const float* crpe_w= (const float*)d_in[6];
    const float* crpe_b= (const float*)d_in[7];
    const float* ln2_w = (const float*)d_in[8];
    const float* ln2_b = (const float*)d_in[9];
    const float* fc1_w = (const float*)d_in[10];
    const float* fc1_b = (const float*)d_in[11];
    const float* dw_w  = (const float*)d_in[12];
    const float* dw_b  = (const float*)d_in[13];
    const float* fc2_w = (const float*)d_in[14];
    const float* fc2_b = (const float*)d_in[15];
    float* spine = (float*)d_out;
    char* ws = (char*)d_ws;

    if (ws_size < WS_NEED) {
        diag_k<<<1, 1, 0, stream>>>(spine, (float)ws_size);
        return;
    }

    bf16*  wq   = (bf16*)(ws + OFF_WQ);
    bf16*  w1   = (bf16*)(ws + OFF_W1);
    bf16*  w2b  = (bf16*)(ws + OFF_W2);
    bf16*  cur  = (bf16*)(ws + OFF_CUR);
    bf16*  qkv  = (bf16*)(ws + OFF_QKV);
    bf16*  vc   = (bf16*)(ws + OFF_VC);
    float* ktvp = (float*)(ws + OFF_KTVP);
    float* csp  = (float*)(ws + OFF_CSP);
    bf16*  hg   = (bf16*)(ws + OFF_HG);
    bf16*  h2a  = (bf16*)(ws + OFF_H2A);
    bf16*  h2b  = (bf16*)(ws + OFF_H2B);

    // weights -> bf16 (w2 native [512][2048])
    f2bf_k<<<(1536 * 512 / 8 + 255) / 256, 256, 0, stream>>>(qkv_w, wq, 1536 * 512);
    f2bf_k<<<(2048 * 512 / 8 + 255) / 256, 256, 0, stream>>>(fc1_w, w1, 2048 * 512);
    f2bf_k<<<(2048 * 512 / 8 + 255) / 256, 256, 0, stream>>>(fc2_w, w2b, 512 * 2048);

    // CPE (fp32, 64-ch groups): spine = x + dwconv(x) + cpe_b
    conv4_k<float, float, true, 1><<<32 * 8 * 4, 256, 0, stream>>>(x, 512, 0, cpe_w, cpe_b, spine, 512, 3);

    const int M = 32768;
    // LN1
    ln_k<<<M / 4, 256, 0, stream>>>(spine, ln1_w, ln1_b, cur);
    // qkv: 768 blocks (XCD-swizzled 256^2 8-phase)
    gemm8p_k<0, 512, 6><<<768, 512, 0, stream>>>(cur, wq, nullptr, qkv, M, 1536);
    // ktv: token-split partials (cur region now dead)
    ktv3_k<<<512, 256, 0, stream>>>(qkv, ktvp, csp);
    // crpe conv on v
    conv4_k<bf16, bf16, false, 2><<<32 * 4 * 4, 256, 0, stream>>>(qkv, 1536, 1024, crpe_w, crpe_b, vc, 512, 2);
    // attention output (fused reduce + MFMA), in place on spine
    attnout3_k<<<32 * 8 * 4, 256, 0, stream>>>(spine, qkv, ktvp, csp, vc);
    // LN2 (rewrites cur; ktvp/csp dead)
    ln_k<<<M / 4, 256, 0, stream>>>(spine, ln2_w, ln2_b, cur);

    // MLP (lifetime-correct order): h0 -> h2a first; h2b (over cur) LAST
    // fc1 back on the 256^2 8-phase kernel (r17/r19 config, measured-best)
    gemm8p_k<1, 512, 4><<<512, 512, 0, stream>>>(cur, w1, fc1_b, hg, M, 1024);
    conv4_k<bf16, bf16, true, 2><<<32 * 8 * 4, 256, 0, stream>>>(hg, 1024, 0, dw_w, dw_b, h2a, 1024, 3);
    gemm8p_k<1, 512, 4><<<512, 512, 0, stream>>>(cur, w1 + (size_t)1024 * 512, fc1_b + 1024, hg, M, 1024);
    conv4_k<bf16, bf16, true, 2><<<32 * 8 * 4, 256, 0, stream>>>(hg, 1024, 0, dw_w + (size_t)1024 * 9, dw_b + 1024, h2b, 1024, 3);
    // fc2: K=2048 dual-A, BM=BN=128, 1024 blocks (2/CU), counted-vmcnt 8-phase
    gemm8ps_k<2, 2048, 4, true><<<1024, 512, 0, stream>>>(h2a, h2b, w2b, fc2_b, spine, nullptr, spine, M, 512);
}